// Round 3
// baseline (458.535 us; speedup 1.0000x reference)
//
#include <hip/hip_runtime.h>
#include <hip/hip_bf16.h>
#include <cstdint>

typedef unsigned short ushortT;
typedef __attribute__((ext_vector_type(8))) short short8;
typedef __attribute__((ext_vector_type(4))) float f32x4;
typedef __attribute__((ext_vector_type(4))) unsigned short us4;

__device__ __forceinline__ ushortT f2bf(float f) {
  union { float f; unsigned u; } v; v.f = f;
  unsigned r = (v.u + 0x7FFFu + ((v.u >> 16) & 1u)) >> 16;
  return (ushortT)r;
}

__device__ __forceinline__ void gl_lds16(const void* g, void* l) {
  __builtin_amdgcn_global_load_lds(
      (__attribute__((address_space(1))) void*)g,
      (__attribute__((address_space(3))) void*)l, 16, 0, 0);
}

// ============ 256x256 tile, 8-wave, swizzled-LDS, counted-vmcnt GEMM =========
// C = A @ B^T + bias, A:(M,K) bf16, B:(N,K) bf16, out f32. K % 64 == 0.
// M % 256 == 0, N % 256 == 0, grid = (M/256)*(N/256), gridDim.x % 8 == 0.
__global__ __launch_bounds__(512) void gemm256(
    const ushortT* __restrict__ A, const ushortT* __restrict__ B,
    int M, int N, int K,
    float* __restrict__ outF, const float* __restrict__ bias)
{
  __shared__ ushortT sA[2][256 * 64];
  __shared__ ushortT sB[2][256 * 64];
  const int tid = threadIdx.x;
  const int wv = tid >> 6, l = tid & 63;
  const int wm = wv >> 2, wn = wv & 3;

  // XCD-aware swizzle: each XCD owns one bn column (B panel L2-resident)
  const int nbm = M >> 8;
  const int nwg = gridDim.x;
  const int cpx = nwg >> 3;
  const int bid = blockIdx.x;
  const int sbid = (bid & 7) * cpx + (bid >> 3);
  const int m0 = (sbid % nbm) * 256;
  const int n0 = (sbid / nbm) * 256;
  const int NK = K >> 6;

  f32x4 acc[8][4] = {};

  // stage issue i (rows i*64..i*64+63) of a 256x64 K-tile, source-swizzled
  auto stageA = [&](int buf, int kt, int i) {
    const int r = i * 64 + (tid >> 3);
    const int ec = (kt << 6) + (((tid & 7) ^ (r & 7)) << 3);
    gl_lds16(A + (size_t)(m0 + r) * (size_t)K + ec,
             &sA[buf][(i * 64 + wv * 8) * 64]);
  };
  auto stageB = [&](int buf, int kt, int i) {
    const int r = i * 64 + (tid >> 3);
    const int ec = (kt << 6) + (((tid & 7) ^ (r & 7)) << 3);
    gl_lds16(B + (size_t)(n0 + r) * (size_t)K + ec,
             &sB[buf][(i * 64 + wv * 8) * 64]);
  };
  // swizzled ds_read of the wave's fragments
  auto dsA = [&](int buf, int qm, short8 (&a)[4][2]) {
#pragma unroll
    for (int fi = 0; fi < 4; ++fi)
#pragma unroll
      for (int ks = 0; ks < 2; ++ks) {
        const int row = wm * 128 + qm * 64 + fi * 16 + (l & 15);
        const int c8 = ks * 4 + (l >> 4);
        a[fi][ks] = *(const short8*)&sA[buf][row * 64 + ((c8 ^ (row & 7)) << 3)];
      }
  };
  auto dsB = [&](int buf, int qn, short8 (&b)[2][2]) {
#pragma unroll
    for (int fj = 0; fj < 2; ++fj)
#pragma unroll
      for (int ks = 0; ks < 2; ++ks) {
        const int row = wn * 64 + qn * 32 + fj * 16 + (l & 15);
        const int c8 = ks * 4 + (l >> 4);
        b[fj][ks] = *(const short8*)&sB[buf][row * 64 + ((c8 ^ (row & 7)) << 3)];
      }
  };
  auto quad = [&](int qm, int qn, short8 (&a)[4][2], short8 (&b)[2][2]) {
    __builtin_amdgcn_s_setprio(1);
#pragma unroll
    for (int fi = 0; fi < 4; ++fi)
#pragma unroll
      for (int fj = 0; fj < 2; ++fj)
#pragma unroll
        for (int ks = 0; ks < 2; ++ks)
          acc[qm * 4 + fi][qn * 2 + fj] = __builtin_amdgcn_mfma_f32_16x16x32_bf16(
              a[fi][ks], b[fj][ks], acc[qm * 4 + fi][qn * 2 + fj], 0, 0, 0);
    __builtin_amdgcn_s_setprio(0);
  };

  // prologue: stage tile 0, drain, sync
  for (int i = 0; i < 4; ++i) { stageA(0, 0, i); stageB(0, 0, i); }
  asm volatile("s_waitcnt vmcnt(0)" ::: "memory");
  asm volatile("s_barrier" ::: "memory");

  for (int kt = 0; kt < NK; ++kt) {
    const int buf = kt & 1, nbuf = buf ^ 1;
    const bool pf = (kt + 1 < NK);
    short8 a[4][2], b[2][2];
    // phase 0: prefetch A(kt+1); compute quadrant (m0,n0)
    if (pf) { stageA(nbuf, kt + 1, 0); stageA(nbuf, kt + 1, 1);
              stageA(nbuf, kt + 1, 2); stageA(nbuf, kt + 1, 3); }
    dsA(buf, 0, a); dsB(buf, 0, b);
    quad(0, 0, a, b);
    asm volatile("s_barrier" ::: "memory");
    // phase 1: prefetch B(kt+1); quadrant (m0,n1)
    if (pf) { stageB(nbuf, kt + 1, 0); stageB(nbuf, kt + 1, 1);
              stageB(nbuf, kt + 1, 2); stageB(nbuf, kt + 1, 3); }
    dsB(buf, 1, b);
    quad(0, 1, a, b);
    asm volatile("s_barrier" ::: "memory");
    // phase 2: quadrant (m1,n0)
    dsA(buf, 1, a); dsB(buf, 0, b);
    quad(1, 0, a, b);
    asm volatile("s_barrier" ::: "memory");
    // phase 3: quadrant (m1,n1); counted drain of kt+1's loads, then sync
    dsB(buf, 1, b);
    quad(1, 1, a, b);
    if (pf) asm volatile("s_waitcnt vmcnt(0)" ::: "memory");
    asm volatile("s_barrier" ::: "memory");
  }

  // epilogue: bias add, f32 store
  const int cc = l & 15, r4 = (l >> 4) * 4;
  float bv[4];
#pragma unroll
  for (int fj = 0; fj < 4; ++fj) bv[fj] = bias[n0 + wn * 64 + fj * 16 + cc];
#pragma unroll
  for (int fi = 0; fi < 8; ++fi)
#pragma unroll
    for (int r = 0; r < 4; ++r) {
      const size_t gm = (size_t)(m0 + wm * 128 + fi * 16 + r4 + r);
#pragma unroll
      for (int fj = 0; fj < 4; ++fj) {
        const int gn = n0 + wn * 64 + fj * 16 + cc;
        outF[gm * (size_t)N + gn] = acc[fi][fj][r] + bv[fj];
      }
    }
}

// ---------------- 128x128 tile GEMM, C = A @ B^T, bf16 in, BK=32 -------------
template <int EPI>
__global__ __launch_bounds__(256) void gemm128(
    const ushortT* __restrict__ A, const ushortT* __restrict__ B,
    int M, int N, int K,
    float* __restrict__ outF, ushortT* __restrict__ outBF,
    const float* __restrict__ bias,
    const float* __restrict__ addend,
    float* __restrict__ S2, float* __restrict__ S4,
    ushortT* __restrict__ sdT, int ldT)
{
  __shared__ ushortT sA[2][128 * 32];
  __shared__ ushortT sB[2][128 * 32];
  const int tid = threadIdx.x;
  const int w = tid >> 6, l = tid & 63;
  const int wr = w >> 1, wc = w & 1;
  const int m0 = blockIdx.x * 128, n0 = blockIdx.y * 128;
  const int NK = K >> 5;

  f32x4 acc[4][4] = {};

  auto stage = [&](int buf, int kt) {
    const int k0 = kt << 5;
    const size_t colA = (size_t)(k0 + (l & 3) * 8);
    const int rb = w * 16 + (l >> 2);
#pragma unroll
    for (int c = 0; c < 2; ++c) {
      gl_lds16(A + (size_t)(m0 + c * 64 + rb) * (size_t)K + colA,
               &sA[buf][c * 2048 + w * 512]);
      gl_lds16(B + (size_t)(n0 + c * 64 + rb) * (size_t)K + colA,
               &sB[buf][c * 2048 + w * 512]);
    }
  };

  stage(0, 0);
  __syncthreads();

  for (int kt = 0; kt < NK; ++kt) {
    const int buf = kt & 1;
    if (kt + 1 < NK) stage(buf ^ 1, kt + 1);
    const int ro = (l & 15) * 32 + (l >> 4) * 8;
    short8 a[4], b[4];
#pragma unroll
    for (int f = 0; f < 4; ++f) {
      a[f] = *(const short8*)&sA[buf][(wr * 64 + f * 16) * 32 + ro];
      b[f] = *(const short8*)&sB[buf][(wc * 64 + f * 16) * 32 + ro];
    }
#pragma unroll
    for (int fi = 0; fi < 4; ++fi)
#pragma unroll
      for (int fj = 0; fj < 4; ++fj)
        acc[fi][fj] = __builtin_amdgcn_mfma_f32_16x16x32_bf16(
            a[fi], b[fj], acc[fi][fj], 0, 0, 0);
    __syncthreads();
  }

  const int r4 = (l >> 4) * 4, cc = l & 15;

  if constexpr (EPI == 0) {
#pragma unroll
    for (int fi = 0; fi < 4; ++fi)
#pragma unroll
      for (int r = 0; r < 4; ++r) {
        const size_t gm = (size_t)(m0 + wr * 64 + fi * 16 + r4 + r);
#pragma unroll
        for (int fj = 0; fj < 4; ++fj) {
          const int gn = n0 + wc * 64 + fj * 16 + cc;
          outF[gm * (size_t)N + gn] = acc[fi][fj][r] + bias[gn];
        }
      }
  } else if constexpr (EPI == 1) {
#pragma unroll
    for (int fi = 0; fi < 4; ++fi)
#pragma unroll
      for (int r = 0; r < 4; ++r) {
        const size_t gm = (size_t)(m0 + wr * 64 + fi * 16 + r4 + r);
#pragma unroll
        for (int fj = 0; fj < 4; ++fj) {
          const int gn = n0 + wc * 64 + fj * 16 + cc;
          outBF[gm * (size_t)N + gn] = f2bf(acc[fi][fj][r]);
        }
      }
  } else {
    __shared__ ushortT tbuf[128 * 136];
#pragma unroll
    for (int fi = 0; fi < 4; ++fi)
#pragma unroll
      for (int r = 0; r < 4; ++r) {
        const int row = wr * 64 + fi * 16 + r4 + r;
        const size_t gm = (size_t)(m0 + row);
        float rs2 = 0.f, rs4 = 0.f;
#pragma unroll
        for (int fj = 0; fj < 4; ++fj) {
          const int col = wc * 64 + fj * 16 + cc;
          float sd = acc[fi][fj][r] + addend[gm * (size_t)N + n0 + col];
          tbuf[col * 136 + row] = f2bf(sd);
          float s2 = sd * sd;
          rs2 += s2;
          rs4 += s2 * s2;
        }
#pragma unroll
        for (int mk = 1; mk < 16; mk <<= 1) {
          rs2 += __shfl_xor(rs2, mk, 16);
          rs4 += __shfl_xor(rs4, mk, 16);
        }
        if (cc == 0) { atomicAdd(&S2[gm], rs2); atomicAdd(&S4[gm], rs4); }
      }
    __syncthreads();
#pragma unroll
    for (int i = 0; i < 8; ++i) {
      const int er = i * 16 + (tid >> 4);
      const int nc = (tid & 15) * 8;
      short8 v = *(const short8*)&tbuf[er * 136 + nc];
      *(short8*)&sdT[(size_t)(n0 + er) * (size_t)ldT + m0 + nc] = v;
    }
  }
}

// ---------------- 64x64 tile GEMM for M = sdT @ sdT^T, writes grad ----------
__global__ __launch_bounds__(256) void mgemm64(
    const ushortT* __restrict__ T, int Dm, int K,
    float* __restrict__ grad, float invN)
{
  __shared__ ushortT sA[2][64 * 32];
  __shared__ ushortT sB[2][64 * 32];
  const int tid = threadIdx.x, w = tid >> 6, l = tid & 63;
  const int wr = w >> 1, wc = w & 1;
  const int i0 = blockIdx.x * 64, j0 = blockIdx.y * 64;
  const int NK = K >> 5;
  f32x4 acc[2][2] = {};

  auto stage = [&](int buf, int kt) {
    const int k0 = kt << 5;
    const size_t col = (size_t)(k0 + (l & 3) * 8);
    const int rb = w * 16 + (l >> 2);
    gl_lds16(T + (size_t)(i0 + rb) * (size_t)K + col, &sA[buf][w * 512]);
    gl_lds16(T + (size_t)(j0 + rb) * (size_t)K + col, &sB[buf][w * 512]);
  };

  stage(0, 0);
  __syncthreads();

  for (int kt = 0; kt < NK; ++kt) {
    const int buf = kt & 1;
    if (kt + 1 < NK) stage(buf ^ 1, kt + 1);
    const int ro = (l & 15) * 32 + (l >> 4) * 8;
    short8 a[2], b[2];
#pragma unroll
    for (int f = 0; f < 2; ++f) {
      a[f] = *(const short8*)&sA[buf][(wr * 32 + f * 16) * 32 + ro];
      b[f] = *(const short8*)&sB[buf][(wc * 32 + f * 16) * 32 + ro];
    }
#pragma unroll
    for (int fi = 0; fi < 2; ++fi)
#pragma unroll
      for (int fj = 0; fj < 2; ++fj)
        acc[fi][fj] = __builtin_amdgcn_mfma_f32_16x16x32_bf16(
            a[fi], b[fj], acc[fi][fj], 0, 0, 0);
    __syncthreads();
  }

  const int r4 = (l >> 4) * 4, cc = l & 15;
#pragma unroll
  for (int fi = 0; fi < 2; ++fi)
#pragma unroll
    for (int r = 0; r < 4; ++r) {
      const int gi = i0 + wr * 32 + fi * 16 + r4 + r;
#pragma unroll
      for (int fj = 0; fj < 2; ++fj) {
        const int gj = j0 + wc * 32 + fj * 16 + cc;
        grad[(size_t)gi * (size_t)Dm + gj] =
            0.5f * (acc[fi][fj][r] * invN) - (gi == gj ? 0.5f : 0.0f);
      }
    }
}

// ---------------- small utility kernels -------------------------------------
__global__ void zero_f32(float* __restrict__ p, int n) {
  int i = blockIdx.x * blockDim.x + threadIdx.x;
  if (i < n) p[i] = 0.f;
}

__global__ void cvt_f32_bf16(const float* __restrict__ in, ushortT* __restrict__ out,
                             size_t n4) {
  size_t i = (size_t)blockIdx.x * blockDim.x + threadIdx.x;
  const size_t stride = (size_t)gridDim.x * blockDim.x;
  const float4* in4 = (const float4*)in;
  for (; i < n4; i += stride) {
    float4 v = in4[i];
    us4 o = { f2bf(v.x), f2bf(v.y), f2bf(v.z), f2bf(v.w) };
    *(us4*)(out + i * 4) = o;
  }
}

__global__ void transposeQ(const float* __restrict__ q, ushortT* __restrict__ qT) {
  const int g = blockIdx.x * 256 + threadIdx.x;  // 131072 threads
  const int d = g >> 7;
  const int k0 = (g & 127) << 3;
  short8 v;
#pragma unroll
  for (int j = 0; j < 8; ++j) v[j] = (short)f2bf(q[(size_t)(k0 + j) * 1024 + d]);
  *(short8*)(qT + (size_t)d * 1024 + k0) = v;
}

__global__ void make_p(const float* __restrict__ q, ushortT* __restrict__ p) {
  const int g = blockIdx.x * 256 + threadIdx.x;  // 131072 threads
  const size_t base = (size_t)g * 8;
  const int e = (int)(base >> 10);
  const int d0 = (int)(base & 1023);
  short8 v;
#pragma unroll
  for (int j = 0; j < 8; ++j) {
    float f = q[base + j] - ((e == d0 + j) ? 1.0f : 0.0f);
    v[j] = (short)f2bf(f);
  }
  *(short8*)(p + base) = v;
}

__global__ void gather_rows(const float* __restrict__ x, const int* __restrict__ idx,
                            float* __restrict__ self32, ushortT* __restrict__ selbf) {
  const int bid = blockIdx.x;  // 0..8191
  const int b = bid >> 10;
  const int row = idx[bid] & 4095;  // harness passes int32; clamp for safety
  const float4* src = (const float4*)(x + ((size_t)b * 4096 + (size_t)row) * 1024);
  const int t = threadIdx.x;  // 256 threads * 4 floats = 1024
  float4 v = src[t];
  *(float4*)(self32 + (size_t)bid * 1024 + t * 4) = v;
  us4 o = { f2bf(v.x), f2bf(v.y), f2bf(v.z), f2bf(v.w) };
  *(us4*)(selbf + (size_t)bid * 1024 + t * 4) = o;
}

__global__ void loss_final(const float* __restrict__ S2, const float* __restrict__ S4,
                           float* __restrict__ out) {
  __shared__ double red0[256];
  __shared__ double red1[256];
  const int t = threadIdx.x;
  double ca = 0.0, wa = 0.0;
  for (int i = t; i < 8192; i += 256) {
    double s2 = (double)S2[i], s4 = (double)S4[i];
    ca += s2 * s2 - s4;
    wa += s4 - 2.0 * s2 + 1024.0;
  }
  red0[t] = ca; red1[t] = wa;
  __syncthreads();
  for (int s = 128; s > 0; s >>= 1) {
    if (t < s) { red0[t] += red0[t + s]; red1[t] += red1[t + s]; }
    __syncthreads();
  }
  if (t == 0) {
    const double inv = 1.0 / (8192.0 * 1024.0 * 1024.0);
    out[0] = (float)(red0[0] * inv);
    out[1] = (float)(red1[0] * inv);
  }
}

// ---------------- launch -----------------------------------------------------
extern "C" void kernel_launch(void* const* d_in, const int* in_sizes, int n_in,
                              void* d_out, int out_size, void* d_ws, size_t ws_size,
                              hipStream_t stream) {
  (void)in_sizes; (void)n_in; (void)out_size;
  const float* x = (const float*)d_in[0];       // (8,4096,1024) f32
  const float* weight = (const float*)d_in[1];  // (2048,1024) f32
  const float* bias = (const float*)d_in[2];    // (2048,) f32
  const float* decorr = (const float*)d_in[3];  // (1024,1024) f32
  const int* sidx = (const int*)d_in[4];        // (8,1024) int32

  if (ws_size < 146866176ULL) return;  // need ~140 MiB scratch

  char* ws = (char*)d_ws;
  ushortT* xbf     = (ushortT*)(ws);              // 33,554,432 bf16
  ushortT* fusedbf = (ushortT*)(ws + 67108864);   //  2,097,152 bf16
  ushortT* wbf     = (ushortT*)(ws + 71303168);   //  2,097,152 bf16
  ushortT* qT      = (ushortT*)(ws + 75497472);   //  1,048,576 bf16
  ushortT* pbf     = (ushortT*)(ws + 77594624);   //  1,048,576 bf16
  float*   self32  = (float*)  (ws + 79691776);   //  8,388,608 f32
  ushortT* selbf   = (ushortT*)(ws + 113246208);  //  8,388,608 bf16
  ushortT* sdT     = (ushortT*)(ws + 130023424);  //  8,388,608 bf16 (1024 x 8192)
  float*   S2      = (float*)  (ws + 146800640);  //  8192 f32
  float*   S4      = (float*)  (ws + 146833408);  //  8192 f32

  float* y = (float*)d_out;                          // 8*4096*2048
  float* grad = y + 67108864ULL;                     // 1024*1024
  float* losses = grad + 1048576ULL;                 // 2 scalars

  zero_f32<<<dim3(64), dim3(256), 0, stream>>>(S2, 16384);  // S2+S4 contiguous
  cvt_f32_bf16<<<dim3(2048), dim3(256), 0, stream>>>(x, xbf, 8388608);
  cvt_f32_bf16<<<dim3(512), dim3(256), 0, stream>>>(weight, wbf, 524288);
  transposeQ<<<dim3(512), dim3(256), 0, stream>>>(decorr, qT);
  make_p<<<dim3(512), dim3(256), 0, stream>>>(decorr, pbf);
  gather_rows<<<dim3(8192), dim3(256), 0, stream>>>(x, sidx, self32, selbf);

  // fused = W @ Q  ->  bf16 (A=wbf 2048xK, B=qT 1024xK)
  gemm128<1><<<dim3(16, 8), dim3(256), 0, stream>>>(
      wbf, qT, 2048, 1024, 1024, nullptr, fusedbf, nullptr, nullptr,
      nullptr, nullptr, nullptr, 0);
  // y = x @ fused^T + bias  — 256^2 8-phase swizzled kernel
  gemm256<<<dim3(1024), dim3(512), 0, stream>>>(
      xbf, fusedbf, 32768, 2048, 1024, y, bias);
  // sd = sel + sel @ P^T; S2/S4 row sums; sdT transposed bf16
  gemm128<2><<<dim3(64, 8), dim3(256), 0, stream>>>(
      selbf, pbf, 8192, 1024, 1024, nullptr, nullptr, nullptr, self32,
      S2, S4, sdT, 8192);
  // grad = 0.5 * (sdT sdT^T)/N - 0.5 I
  mgemm64<<<dim3(16, 16), dim3(256), 0, stream>>>(sdT, 1024, 8192, grad,
                                                  1.0f / 8192.0f);
  loss_final<<<dim3(1), dim3(256), 0, stream>>>(S2, S4, losses);
}

// Round 4
// 449.098 us; speedup vs baseline: 1.0210x; 1.0210x over previous
//
#include <hip/hip_runtime.h>
#include <hip/hip_bf16.h>
#include <cstdint>

typedef unsigned short ushortT;
typedef __attribute__((ext_vector_type(8))) short short8;
typedef __attribute__((ext_vector_type(4))) float f32x4;
typedef __attribute__((ext_vector_type(4))) unsigned short us4;

__device__ __forceinline__ ushortT f2bf(float f) {
  union { float f; unsigned u; } v; v.f = f;
  unsigned r = (v.u + 0x7FFFu + ((v.u >> 16) & 1u)) >> 16;
  return (ushortT)r;
}

__device__ __forceinline__ void gl_lds16(const void* g, void* l) {
  __builtin_amdgcn_global_load_lds(
      (__attribute__((address_space(1))) void*)g,
      (__attribute__((address_space(3))) void*)l, 16, 0, 0);
}

// ============ 256x256 tile, 8-wave, depth-3 counted-vmcnt GEMM ===============
// C = A @ B^T + bias. A:(M,K) bf16, B:(N,K) bf16, out f32.
// BK=32, 4 LDS buffers (128 KiB total), prefetch 3 K-steps ahead.
// vmcnt discipline: 4 loads/thread/K-step; steady state 12 outstanding;
// wait vmcnt(8) retires exactly the oldest K-step. Never drains to 0 mid-loop.
// LDS swizzle (64B rows): granule' = granule ^ ((row>>1)&3). Fragment read
// (16 rows x 4 granules per ds_read_b128) then loads 8 words/bank evenly.
__global__ __launch_bounds__(512) void gemm256(
    const ushortT* __restrict__ A, const ushortT* __restrict__ B,
    int M, int N, int K,
    float* __restrict__ outF, const float* __restrict__ bias)
{
  __shared__ ushortT sA[4][256 * 32];
  __shared__ ushortT sB[4][256 * 32];
  const int tid = threadIdx.x;
  const int wv = tid >> 6, l = tid & 63;
  const int wm = wv >> 2, wn = wv & 3;

  // XCD-aware swizzle (gridDim.x % 8 == 0 -> bijective)
  const int nbm = M >> 8;
  const int cpx = gridDim.x >> 3;
  const int bid = blockIdx.x;
  const int sbid = (bid & 7) * cpx + (bid >> 3);
  const int m0 = (sbid % nbm) * 256;
  const int n0 = (sbid / nbm) * 256;
  const int NK = K >> 5;

  f32x4 acc[8][4] = {};

  const ushortT* Abase = A + (size_t)m0 * (size_t)K;
  const ushortT* Bbase = B + (size_t)n0 * (size_t)K;

  const int srow = tid >> 2;  // 0..127 (staging row within half)
  const int sg = tid & 3;     // staging granule

  // stage one 256x32 K-step of one array: 2 x gl_lds16 per thread
  auto stage = [&](const ushortT* __restrict__ P, ushortT(*S)[256 * 32], int kt) {
    const int b = kt & 3;
#pragma unroll
    for (int i = 0; i < 2; ++i) {
      const int r = i * 128 + srow;
      const int gs = sg ^ ((r >> 1) & 3);  // inverse-swizzled global source
      gl_lds16(P + (size_t)r * (size_t)K + (kt << 5) + (gs << 3),
               &S[b][(i * 128 + (wv << 4)) * 32]);
    }
  };

  // fragment-read constants
  const int fr = l & 15;                    // row within 16-row fragment
  const int colsw = (((l >> 4) ^ ((fr >> 1) & 3)) << 3);  // swizzled granule
  const int arow = wm * 128 + fr;
  const int brow = wn * 64 + fr;

  // prologue: prefetch K-steps 0..2
  for (int t = 0; t < 3 && t < NK; ++t) { stage(Abase, sA, t); stage(Bbase, sB, t); }

  for (int kt = 0; kt < NK; ++kt) {
    // counted wait: retire exactly the oldest K-step's loads
    if (kt + 2 < NK)      asm volatile("s_waitcnt vmcnt(8)" ::: "memory");
    else if (kt + 1 < NK) asm volatile("s_waitcnt vmcnt(4)" ::: "memory");
    else                  asm volatile("s_waitcnt vmcnt(0)" ::: "memory");
    __builtin_amdgcn_s_barrier();
    // issue next prefetch FIRST (T3 recipe), writes buf (kt-1)&3 (safe: its
    // readers retired their ds_reads before arriving at this barrier)
    if (kt + 3 < NK) { stage(Abase, sA, kt + 3); stage(Bbase, sB, kt + 3); }

    const int b = kt & 3;
    short8 a[8], bb[4];
#pragma unroll
    for (int fi = 0; fi < 8; ++fi)
      a[fi] = *(const short8*)&sA[b][(arow + fi * 16) * 32 + colsw];
#pragma unroll
    for (int fj = 0; fj < 4; ++fj)
      bb[fj] = *(const short8*)&sB[b][(brow + fj * 16) * 32 + colsw];

    __builtin_amdgcn_s_setprio(1);
#pragma unroll
    for (int fi = 0; fi < 8; ++fi)
#pragma unroll
      for (int fj = 0; fj < 4; ++fj)
        acc[fi][fj] = __builtin_amdgcn_mfma_f32_16x16x32_bf16(
            a[fi], bb[fj], acc[fi][fj], 0, 0, 0);
    __builtin_amdgcn_s_setprio(0);
  }

  // epilogue: bias add, f32 store
  const int cc = l & 15, r4 = (l >> 4) * 4;
  float bv[4];
#pragma unroll
  for (int fj = 0; fj < 4; ++fj) bv[fj] = bias[n0 + wn * 64 + fj * 16 + cc];
#pragma unroll
  for (int fi = 0; fi < 8; ++fi)
#pragma unroll
    for (int r = 0; r < 4; ++r) {
      const size_t gm = (size_t)(m0 + wm * 128 + fi * 16 + r4 + r);
#pragma unroll
      for (int fj = 0; fj < 4; ++fj) {
        const int gn = n0 + wn * 64 + fj * 16 + cc;
        outF[gm * (size_t)N + gn] = acc[fi][fj][r] + bv[fj];
      }
    }
}

// ---------------- 128x128 tile GEMM, C = A @ B^T, bf16 in, BK=32 -------------
template <int EPI>
__global__ __launch_bounds__(256) void gemm128(
    const ushortT* __restrict__ A, const ushortT* __restrict__ B,
    int M, int N, int K,
    float* __restrict__ outF, ushortT* __restrict__ outBF,
    const float* __restrict__ bias,
    const float* __restrict__ addend,
    float* __restrict__ S2, float* __restrict__ S4,
    ushortT* __restrict__ sdT, int ldT)
{
  __shared__ ushortT sA[2][128 * 32];
  __shared__ ushortT sB[2][128 * 32];
  const int tid = threadIdx.x;
  const int w = tid >> 6, l = tid & 63;
  const int wr = w >> 1, wc = w & 1;
  const int m0 = blockIdx.x * 128, n0 = blockIdx.y * 128;
  const int NK = K >> 5;

  f32x4 acc[4][4] = {};

  auto stage = [&](int buf, int kt) {
    const int k0 = kt << 5;
    const size_t colA = (size_t)(k0 + (l & 3) * 8);
    const int rb = w * 16 + (l >> 2);
#pragma unroll
    for (int c = 0; c < 2; ++c) {
      gl_lds16(A + (size_t)(m0 + c * 64 + rb) * (size_t)K + colA,
               &sA[buf][c * 2048 + w * 512]);
      gl_lds16(B + (size_t)(n0 + c * 64 + rb) * (size_t)K + colA,
               &sB[buf][c * 2048 + w * 512]);
    }
  };

  stage(0, 0);
  __syncthreads();

  for (int kt = 0; kt < NK; ++kt) {
    const int buf = kt & 1;
    if (kt + 1 < NK) stage(buf ^ 1, kt + 1);
    const int ro = (l & 15) * 32 + (l >> 4) * 8;
    short8 a[4], b[4];
#pragma unroll
    for (int f = 0; f < 4; ++f) {
      a[f] = *(const short8*)&sA[buf][(wr * 64 + f * 16) * 32 + ro];
      b[f] = *(const short8*)&sB[buf][(wc * 64 + f * 16) * 32 + ro];
    }
#pragma unroll
    for (int fi = 0; fi < 4; ++fi)
#pragma unroll
      for (int fj = 0; fj < 4; ++fj)
        acc[fi][fj] = __builtin_amdgcn_mfma_f32_16x16x32_bf16(
            a[fi], b[fj], acc[fi][fj], 0, 0, 0);
    __syncthreads();
  }

  const int r4 = (l >> 4) * 4, cc = l & 15;

  if constexpr (EPI == 0) {
#pragma unroll
    for (int fi = 0; fi < 4; ++fi)
#pragma unroll
      for (int r = 0; r < 4; ++r) {
        const size_t gm = (size_t)(m0 + wr * 64 + fi * 16 + r4 + r);
#pragma unroll
        for (int fj = 0; fj < 4; ++fj) {
          const int gn = n0 + wc * 64 + fj * 16 + cc;
          outF[gm * (size_t)N + gn] = acc[fi][fj][r] + bias[gn];
        }
      }
  } else if constexpr (EPI == 1) {
#pragma unroll
    for (int fi = 0; fi < 4; ++fi)
#pragma unroll
      for (int r = 0; r < 4; ++r) {
        const size_t gm = (size_t)(m0 + wr * 64 + fi * 16 + r4 + r);
#pragma unroll
        for (int fj = 0; fj < 4; ++fj) {
          const int gn = n0 + wc * 64 + fj * 16 + cc;
          outBF[gm * (size_t)N + gn] = f2bf(acc[fi][fj][r]);
        }
      }
  } else {
    __shared__ ushortT tbuf[128 * 136];
#pragma unroll
    for (int fi = 0; fi < 4; ++fi)
#pragma unroll
      for (int r = 0; r < 4; ++r) {
        const int row = wr * 64 + fi * 16 + r4 + r;
        const size_t gm = (size_t)(m0 + row);
        float rs2 = 0.f, rs4 = 0.f;
#pragma unroll
        for (int fj = 0; fj < 4; ++fj) {
          const int col = wc * 64 + fj * 16 + cc;
          float sd = acc[fi][fj][r] + addend[gm * (size_t)N + n0 + col];
          tbuf[col * 136 + row] = f2bf(sd);
          float s2 = sd * sd;
          rs2 += s2;
          rs4 += s2 * s2;
        }
#pragma unroll
        for (int mk = 1; mk < 16; mk <<= 1) {
          rs2 += __shfl_xor(rs2, mk, 16);
          rs4 += __shfl_xor(rs4, mk, 16);
        }
        if (cc == 0) { atomicAdd(&S2[gm], rs2); atomicAdd(&S4[gm], rs4); }
      }
    __syncthreads();
#pragma unroll
    for (int i = 0; i < 8; ++i) {
      const int er = i * 16 + (tid >> 4);
      const int nc = (tid & 15) * 8;
      short8 v = *(const short8*)&tbuf[er * 136 + nc];
      *(short8*)&sdT[(size_t)(n0 + er) * (size_t)ldT + m0 + nc] = v;
    }
  }
}

// ---------------- 64x64 tile GEMM for M = sdT @ sdT^T, writes grad ----------
__global__ __launch_bounds__(256) void mgemm64(
    const ushortT* __restrict__ T, int Dm, int K,
    float* __restrict__ grad, float invN)
{
  __shared__ ushortT sA[2][64 * 32];
  __shared__ ushortT sB[2][64 * 32];
  const int tid = threadIdx.x, w = tid >> 6, l = tid & 63;
  const int wr = w >> 1, wc = w & 1;
  const int i0 = blockIdx.x * 64, j0 = blockIdx.y * 64;
  const int NK = K >> 5;
  f32x4 acc[2][2] = {};

  auto stage = [&](int buf, int kt) {
    const int k0 = kt << 5;
    const size_t col = (size_t)(k0 + (l & 3) * 8);
    const int rb = w * 16 + (l >> 2);
    gl_lds16(T + (size_t)(i0 + rb) * (size_t)K + col, &sA[buf][w * 512]);
    gl_lds16(T + (size_t)(j0 + rb) * (size_t)K + col, &sB[buf][w * 512]);
  };

  stage(0, 0);
  __syncthreads();

  for (int kt = 0; kt < NK; ++kt) {
    const int buf = kt & 1;
    if (kt + 1 < NK) stage(buf ^ 1, kt + 1);
    const int ro = (l & 15) * 32 + (l >> 4) * 8;
    short8 a[2], b[2];
#pragma unroll
    for (int f = 0; f < 2; ++f) {
      a[f] = *(const short8*)&sA[buf][(wr * 32 + f * 16) * 32 + ro];
      b[f] = *(const short8*)&sB[buf][(wc * 32 + f * 16) * 32 + ro];
    }
#pragma unroll
    for (int fi = 0; fi < 2; ++fi)
#pragma unroll
      for (int fj = 0; fj < 2; ++fj)
        acc[fi][fj] = __builtin_amdgcn_mfma_f32_16x16x32_bf16(
            a[fi], b[fj], acc[fi][fj], 0, 0, 0);
    __syncthreads();
  }

  const int r4 = (l >> 4) * 4, cc = l & 15;
#pragma unroll
  for (int fi = 0; fi < 2; ++fi)
#pragma unroll
    for (int r = 0; r < 4; ++r) {
      const int gi = i0 + wr * 32 + fi * 16 + r4 + r;
#pragma unroll
      for (int fj = 0; fj < 2; ++fj) {
        const int gj = j0 + wc * 32 + fj * 16 + cc;
        grad[(size_t)gi * (size_t)Dm + gj] =
            0.5f * (acc[fi][fj][r] * invN) - (gi == gj ? 0.5f : 0.0f);
      }
    }
}

// ---------------- small utility kernels -------------------------------------
__global__ void zero_f32(float* __restrict__ p, int n) {
  int i = blockIdx.x * blockDim.x + threadIdx.x;
  if (i < n) p[i] = 0.f;
}

__global__ void cvt_f32_bf16(const float* __restrict__ in, ushortT* __restrict__ out,
                             size_t n4) {
  size_t i = (size_t)blockIdx.x * blockDim.x + threadIdx.x;
  const size_t stride = (size_t)gridDim.x * blockDim.x;
  const float4* in4 = (const float4*)in;
  for (; i < n4; i += stride) {
    float4 v = in4[i];
    us4 o = { f2bf(v.x), f2bf(v.y), f2bf(v.z), f2bf(v.w) };
    *(us4*)(out + i * 4) = o;
  }
}

__global__ void transposeQ(const float* __restrict__ q, ushortT* __restrict__ qT) {
  const int g = blockIdx.x * 256 + threadIdx.x;  // 131072 threads
  const int d = g >> 7;
  const int k0 = (g & 127) << 3;
  short8 v;
#pragma unroll
  for (int j = 0; j < 8; ++j) v[j] = (short)f2bf(q[(size_t)(k0 + j) * 1024 + d]);
  *(short8*)(qT + (size_t)d * 1024 + k0) = v;
}

__global__ void make_p(const float* __restrict__ q, ushortT* __restrict__ p) {
  const int g = blockIdx.x * 256 + threadIdx.x;  // 131072 threads
  const size_t base = (size_t)g * 8;
  const int e = (int)(base >> 10);
  const int d0 = (int)(base & 1023);
  short8 v;
#pragma unroll
  for (int j = 0; j < 8; ++j) {
    float f = q[base + j] - ((e == d0 + j) ? 1.0f : 0.0f);
    v[j] = (short)f2bf(f);
  }
  *(short8*)(p + base) = v;
}

__global__ void gather_rows(const float* __restrict__ x, const int* __restrict__ idx,
                            float* __restrict__ self32, ushortT* __restrict__ selbf) {
  const int bid = blockIdx.x;  // 0..8191
  const int b = bid >> 10;
  const int row = idx[bid] & 4095;  // harness passes int32; clamp for safety
  const float4* src = (const float4*)(x + ((size_t)b * 4096 + (size_t)row) * 1024);
  const int t = threadIdx.x;  // 256 threads * 4 floats = 1024
  float4 v = src[t];
  *(float4*)(self32 + (size_t)bid * 1024 + t * 4) = v;
  us4 o = { f2bf(v.x), f2bf(v.y), f2bf(v.z), f2bf(v.w) };
  *(us4*)(selbf + (size_t)bid * 1024 + t * 4) = o;
}

__global__ void loss_final(const float* __restrict__ S2, const float* __restrict__ S4,
                           float* __restrict__ out) {
  __shared__ double red0[256];
  __shared__ double red1[256];
  const int t = threadIdx.x;
  double ca = 0.0, wa = 0.0;
  for (int i = t; i < 8192; i += 256) {
    double s2 = (double)S2[i], s4 = (double)S4[i];
    ca += s2 * s2 - s4;
    wa += s4 - 2.0 * s2 + 1024.0;
  }
  red0[t] = ca; red1[t] = wa;
  __syncthreads();
  for (int s = 128; s > 0; s >>= 1) {
    if (t < s) { red0[t] += red0[t + s]; red1[t] += red1[t + s]; }
    __syncthreads();
  }
  if (t == 0) {
    const double inv = 1.0 / (8192.0 * 1024.0 * 1024.0);
    out[0] = (float)(red0[0] * inv);
    out[1] = (float)(red1[0] * inv);
  }
}

// ---------------- launch -----------------------------------------------------
extern "C" void kernel_launch(void* const* d_in, const int* in_sizes, int n_in,
                              void* d_out, int out_size, void* d_ws, size_t ws_size,
                              hipStream_t stream) {
  (void)in_sizes; (void)n_in; (void)out_size;
  const float* x = (const float*)d_in[0];       // (8,4096,1024) f32
  const float* weight = (const float*)d_in[1];  // (2048,1024) f32
  const float* bias = (const float*)d_in[2];    // (2048,) f32
  const float* decorr = (const float*)d_in[3];  // (1024,1024) f32
  const int* sidx = (const int*)d_in[4];        // (8,1024) int32

  if (ws_size < 146866176ULL) return;  // need ~140 MiB scratch

  char* ws = (char*)d_ws;
  ushortT* xbf     = (ushortT*)(ws);              // 33,554,432 bf16
  ushortT* fusedbf = (ushortT*)(ws + 67108864);   //  2,097,152 bf16
  ushortT* wbf     = (ushortT*)(ws + 71303168);   //  2,097,152 bf16
  ushortT* qT      = (ushortT*)(ws + 75497472);   //  1,048,576 bf16
  ushortT* pbf     = (ushortT*)(ws + 77594624);   //  1,048,576 bf16
  float*   self32  = (float*)  (ws + 79691776);   //  8,388,608 f32
  ushortT* selbf   = (ushortT*)(ws + 113246208);  //  8,388,608 bf16
  ushortT* sdT     = (ushortT*)(ws + 130023424);  //  8,388,608 bf16 (1024 x 8192)
  float*   S2      = (float*)  (ws + 146800640);  //  8192 f32
  float*   S4      = (float*)  (ws + 146833408);  //  8192 f32

  float* y = (float*)d_out;                          // 8*4096*2048
  float* grad = y + 67108864ULL;                     // 1024*1024
  float* losses = grad + 1048576ULL;                 // 2 scalars

  zero_f32<<<dim3(64), dim3(256), 0, stream>>>(S2, 16384);  // S2+S4 contiguous
  cvt_f32_bf16<<<dim3(2048), dim3(256), 0, stream>>>(x, xbf, 8388608);
  cvt_f32_bf16<<<dim3(512), dim3(256), 0, stream>>>(weight, wbf, 524288);
  transposeQ<<<dim3(512), dim3(256), 0, stream>>>(decorr, qT);
  make_p<<<dim3(512), dim3(256), 0, stream>>>(decorr, pbf);
  gather_rows<<<dim3(8192), dim3(256), 0, stream>>>(x, sidx, self32, selbf);

  // fused = W @ Q  ->  bf16 (A=wbf 2048xK, B=qT 1024xK)
  gemm128<1><<<dim3(16, 8), dim3(256), 0, stream>>>(
      wbf, qT, 2048, 1024, 1024, nullptr, fusedbf, nullptr, nullptr,
      nullptr, nullptr, nullptr, 0);
  // y = x @ fused^T + bias  — 256^2 depth-3 counted-vmcnt kernel
  gemm256<<<dim3(1024), dim3(512), 0, stream>>>(
      xbf, fusedbf, 32768, 2048, 1024, y, bias);
  // sd = sel + sel @ P^T; S2/S4 row sums; sdT transposed bf16
  gemm128<2><<<dim3(64, 8), dim3(256), 0, stream>>>(
      selbf, pbf, 8192, 1024, 1024, nullptr, nullptr, nullptr, self32,
      S2, S4, sdT, 8192);
  // grad = 0.5 * (sdT sdT^T)/N - 0.5 I
  mgemm64<<<dim3(16, 16), dim3(256), 0, stream>>>(sdT, 1024, 8192, grad,
                                                  1.0f / 8192.0f);
  loss_final<<<dim3(1), dim3(256), 0, stream>>>(S2, S4, losses);
}

// Round 6
// 398.488 us; speedup vs baseline: 1.1507x; 1.1270x over previous
//
#include <hip/hip_runtime.h>
#include <hip/hip_bf16.h>
#include <cstdint>

typedef unsigned short ushortT;
typedef __attribute__((ext_vector_type(8))) short short8;
typedef __attribute__((ext_vector_type(4))) float f32x4;
typedef __attribute__((ext_vector_type(4))) unsigned short us4;

__device__ __forceinline__ ushortT f2bf(float f) {
  union { float f; unsigned u; } v; v.f = f;
  unsigned r = (v.u + 0x7FFFu + ((v.u >> 16) & 1u)) >> 16;
  return (ushortT)r;
}

__device__ __forceinline__ void gl_lds16(const void* g, void* l) {
  __builtin_amdgcn_global_load_lds(
      (__attribute__((address_space(1))) void*)g,
      (__attribute__((address_space(3))) void*)l, 16, 0, 0);
}

// ============ 256x256 tile, 8-wave, depth-3 counted-vmcnt GEMM ===============
// C = A @ B^T + bias. A:(M,K) bf16, B:(N,K) bf16, out f32 (nontemporal).
// BK=32, 4 LDS buffers (128 KiB), prefetch 3 K-steps ahead, counted vmcnt.
// XCD swizzle: each XCD owns a contiguous 16-m-panel stripe (A LLC-resident).
// Epilogue: LDS-transpose -> 1KB-contiguous nontemporal f32x4 stores.
__global__ __launch_bounds__(512) void gemm256(
    const ushortT* __restrict__ A, const ushortT* __restrict__ B,
    int M, int N, int K,
    float* __restrict__ outF, const float* __restrict__ bias)
{
  __shared__ ushortT smem[2 * 4 * 256 * 32];  // 128 KiB: sA(4 bufs) | sB(4 bufs)
  ushortT(*sA)[256 * 32] = (ushortT(*)[256 * 32])smem;
  ushortT(*sB)[256 * 32] = (ushortT(*)[256 * 32])(smem + 4 * 256 * 32);

  const int tid = threadIdx.x;
  const int wv = tid >> 6, l = tid & 63;
  const int wm = wv >> 2, wn = wv & 3;

  // XCD swizzle: xcd = bid&7 owns m-panels [xcd*16, xcd*16+16), n varies slow.
  // q = bid>>3 in [0,128): m_idx = xcd*16 + (q&15), n_idx = q>>4. Bijective.
  const int bid = blockIdx.x;
  const int xcd = bid & 7, q = bid >> 3;
  const int m0 = (xcd * 16 + (q & 15)) * 256;
  const int n0 = (q >> 4) * 256;
  const int NK = K >> 5;

  f32x4 acc[8][4] = {};

  const ushortT* Abase = A + (size_t)m0 * (size_t)K;
  const ushortT* Bbase = B + (size_t)n0 * (size_t)K;

  const int srow = tid >> 2;  // 0..127
  const int sg = tid & 3;     // staging granule

  auto stage = [&](const ushortT* __restrict__ P, ushortT(*S)[256 * 32], int kt) {
    const int b = kt & 3;
#pragma unroll
    for (int i = 0; i < 2; ++i) {
      const int r = i * 128 + srow;
      const int gs = sg ^ ((r >> 1) & 3);  // inverse-swizzled global source
      gl_lds16(P + (size_t)r * (size_t)K + (kt << 5) + (gs << 3),
               &S[b][(i * 128 + (wv << 4)) * 32]);
    }
  };

  const int fr = l & 15;
  const int colsw = (((l >> 4) ^ ((fr >> 1) & 3)) << 3);
  const int arow = wm * 128 + fr;
  const int brow = wn * 64 + fr;

  for (int t = 0; t < 3 && t < NK; ++t) { stage(Abase, sA, t); stage(Bbase, sB, t); }

  for (int kt = 0; kt < NK; ++kt) {
    if (kt + 2 < NK)      asm volatile("s_waitcnt vmcnt(8)" ::: "memory");
    else if (kt + 1 < NK) asm volatile("s_waitcnt vmcnt(4)" ::: "memory");
    else                  asm volatile("s_waitcnt vmcnt(0)" ::: "memory");
    __builtin_amdgcn_s_barrier();
    if (kt + 3 < NK) { stage(Abase, sA, kt + 3); stage(Bbase, sB, kt + 3); }

    const int b = kt & 3;
    short8 a[8], bb[4];
#pragma unroll
    for (int fi = 0; fi < 8; ++fi)
      a[fi] = *(const short8*)&sA[b][(arow + fi * 16) * 32 + colsw];
#pragma unroll
    for (int fj = 0; fj < 4; ++fj)
      bb[fj] = *(const short8*)&sB[b][(brow + fj * 16) * 32 + colsw];

    __builtin_amdgcn_s_setprio(1);
#pragma unroll
    for (int fi = 0; fi < 8; ++fi)
#pragma unroll
      for (int fj = 0; fj < 4; ++fj)
        acc[fi][fj] = __builtin_amdgcn_mfma_f32_16x16x32_bf16(
            a[fi], bb[fj], acc[fi][fj], 0, 0, 0);
    __builtin_amdgcn_s_setprio(0);
  }

  // ---- epilogue: LDS transpose -> contiguous nontemporal f32x4 stores ----
  const int cc = l & 15, r4 = (l >> 4) * 4;
  float bv[4];
#pragma unroll
  for (int fj = 0; fj < 4; ++fj) bv[fj] = bias[n0 + wn * 64 + fj * 16 + cc];

  float* lbuf = (float*)smem;  // 128 rows x 256 cols f32 = 128 KiB
#pragma unroll
  for (int s = 0; s < 2; ++s) {
    __syncthreads();
    if (wm == s) {
#pragma unroll
      for (int fi = 0; fi < 8; ++fi)
#pragma unroll
        for (int r = 0; r < 4; ++r) {
          const int row = fi * 16 + r4 + r;
#pragma unroll
          for (int fj = 0; fj < 4; ++fj)
            lbuf[row * 256 + wn * 64 + fj * 16 + cc] = acc[fi][fj][r] + bv[fj];
        }
    }
    __syncthreads();
#pragma unroll
    for (int k = 0; k < 16; ++k) {
      const int f = k * 512 + tid;     // f32x4 index in swath
      const int row = f >> 6, c4 = f & 63;
      f32x4 v = *(const f32x4*)&lbuf[row * 256 + c4 * 4];
      __builtin_nontemporal_store(
          v, (f32x4*)&outF[(size_t)(m0 + s * 128 + row) * (size_t)N + n0 + c4 * 4]);
    }
  }
}

// ---------------- 128x128 tile GEMM, C = A @ B^T, bf16 in, BK=32 -------------
template <int EPI>
__global__ __launch_bounds__(256) void gemm128(
    const ushortT* __restrict__ A, const ushortT* __restrict__ B,
    int M, int N, int K,
    float* __restrict__ outF, ushortT* __restrict__ outBF,
    const float* __restrict__ bias,
    const float* __restrict__ addend,
    float* __restrict__ S2, float* __restrict__ S4,
    ushortT* __restrict__ sdT, int ldT)
{
  __shared__ ushortT sA[2][128 * 32];
  __shared__ ushortT sB[2][128 * 32];
  const int tid = threadIdx.x;
  const int w = tid >> 6, l = tid & 63;
  const int wr = w >> 1, wc = w & 1;
  const int m0 = blockIdx.x * 128, n0 = blockIdx.y * 128;
  const int NK = K >> 5;

  f32x4 acc[4][4] = {};

  auto stage = [&](int buf, int kt) {
    const int k0 = kt << 5;
    const size_t colA = (size_t)(k0 + (l & 3) * 8);
    const int rb = w * 16 + (l >> 2);
#pragma unroll
    for (int c = 0; c < 2; ++c) {
      gl_lds16(A + (size_t)(m0 + c * 64 + rb) * (size_t)K + colA,
               &sA[buf][c * 2048 + w * 512]);
      gl_lds16(B + (size_t)(n0 + c * 64 + rb) * (size_t)K + colA,
               &sB[buf][c * 2048 + w * 512]);
    }
  };

  stage(0, 0);
  __syncthreads();

  for (int kt = 0; kt < NK; ++kt) {
    const int buf = kt & 1;
    if (kt + 1 < NK) stage(buf ^ 1, kt + 1);
    const int ro = (l & 15) * 32 + (l >> 4) * 8;
    short8 a[4], b[4];
#pragma unroll
    for (int f = 0; f < 4; ++f) {
      a[f] = *(const short8*)&sA[buf][(wr * 64 + f * 16) * 32 + ro];
      b[f] = *(const short8*)&sB[buf][(wc * 64 + f * 16) * 32 + ro];
    }
#pragma unroll
    for (int fi = 0; fi < 4; ++fi)
#pragma unroll
      for (int fj = 0; fj < 4; ++fj)
        acc[fi][fj] = __builtin_amdgcn_mfma_f32_16x16x32_bf16(
            a[fi], b[fj], acc[fi][fj], 0, 0, 0);
    __syncthreads();
  }

  const int r4 = (l >> 4) * 4, cc = l & 15;

  if constexpr (EPI == 0) {
#pragma unroll
    for (int fi = 0; fi < 4; ++fi)
#pragma unroll
      for (int r = 0; r < 4; ++r) {
        const size_t gm = (size_t)(m0 + wr * 64 + fi * 16 + r4 + r);
#pragma unroll
        for (int fj = 0; fj < 4; ++fj) {
          const int gn = n0 + wc * 64 + fj * 16 + cc;
          outF[gm * (size_t)N + gn] = acc[fi][fj][r] + bias[gn];
        }
      }
  } else if constexpr (EPI == 1) {
#pragma unroll
    for (int fi = 0; fi < 4; ++fi)
#pragma unroll
      for (int r = 0; r < 4; ++r) {
        const size_t gm = (size_t)(m0 + wr * 64 + fi * 16 + r4 + r);
#pragma unroll
        for (int fj = 0; fj < 4; ++fj) {
          const int gn = n0 + wc * 64 + fj * 16 + cc;
          outBF[gm * (size_t)N + gn] = f2bf(acc[fi][fj][r]);
        }
      }
  } else {
    __shared__ ushortT tbuf[128 * 136];
#pragma unroll
    for (int fi = 0; fi < 4; ++fi)
#pragma unroll
      for (int r = 0; r < 4; ++r) {
        const int row = wr * 64 + fi * 16 + r4 + r;
        const size_t gm = (size_t)(m0 + row);
        float rs2 = 0.f, rs4 = 0.f;
#pragma unroll
        for (int fj = 0; fj < 4; ++fj) {
          const int col = wc * 64 + fj * 16 + cc;
          float sd = acc[fi][fj][r] + addend[gm * (size_t)N + n0 + col];
          tbuf[col * 136 + row] = f2bf(sd);
          float s2 = sd * sd;
          rs2 += s2;
          rs4 += s2 * s2;
        }
#pragma unroll
        for (int mk = 1; mk < 16; mk <<= 1) {
          rs2 += __shfl_xor(rs2, mk, 16);
          rs4 += __shfl_xor(rs4, mk, 16);
        }
        if (cc == 0) { atomicAdd(&S2[gm], rs2); atomicAdd(&S4[gm], rs4); }
      }
    __syncthreads();
#pragma unroll
    for (int i = 0; i < 8; ++i) {
      const int er = i * 16 + (tid >> 4);
      const int nc = (tid & 15) * 8;
      short8 v = *(const short8*)&tbuf[er * 136 + nc];
      *(short8*)&sdT[(size_t)(n0 + er) * (size_t)ldT + m0 + nc] = v;
    }
  }
}

// ---------------- 64x64 tile GEMM for M = sdT @ sdT^T, writes grad ----------
__global__ __launch_bounds__(256) void mgemm64(
    const ushortT* __restrict__ T, int Dm, int K,
    float* __restrict__ grad, float invN)
{
  __shared__ ushortT sA[2][64 * 32];
  __shared__ ushortT sB[2][64 * 32];
  const int tid = threadIdx.x, w = tid >> 6, l = tid & 63;
  const int wr = w >> 1, wc = w & 1;
  const int i0 = blockIdx.x * 64, j0 = blockIdx.y * 64;
  const int NK = K >> 5;
  f32x4 acc[2][2] = {};

  auto stage = [&](int buf, int kt) {
    const int k0 = kt << 5;
    const size_t col = (size_t)(k0 + (l & 3) * 8);
    const int rb = w * 16 + (l >> 2);
    gl_lds16(T + (size_t)(i0 + rb) * (size_t)K + col, &sA[buf][w * 512]);
    gl_lds16(T + (size_t)(j0 + rb) * (size_t)K + col, &sB[buf][w * 512]);
  };

  stage(0, 0);
  __syncthreads();

  for (int kt = 0; kt < NK; ++kt) {
    const int buf = kt & 1;
    if (kt + 1 < NK) stage(buf ^ 1, kt + 1);
    const int ro = (l & 15) * 32 + (l >> 4) * 8;
    short8 a[2], b[2];
#pragma unroll
    for (int f = 0; f < 2; ++f) {
      a[f] = *(const short8*)&sA[buf][(wr * 32 + f * 16) * 32 + ro];
      b[f] = *(const short8*)&sB[buf][(wc * 32 + f * 16) * 32 + ro];
    }
#pragma unroll
    for (int fi = 0; fi < 2; ++fi)
#pragma unroll
      for (int fj = 0; fj < 2; ++fj)
        acc[fi][fj] = __builtin_amdgcn_mfma_f32_16x16x32_bf16(
            a[fi], b[fj], acc[fi][fj], 0, 0, 0);
    __syncthreads();
  }

  const int r4 = (l >> 4) * 4, cc = l & 15;
#pragma unroll
  for (int fi = 0; fi < 2; ++fi)
#pragma unroll
    for (int r = 0; r < 4; ++r) {
      const int gi = i0 + wr * 32 + fi * 16 + r4 + r;
#pragma unroll
      for (int fj = 0; fj < 2; ++fj) {
        const int gj = j0 + wc * 32 + fj * 16 + cc;
        grad[(size_t)gi * (size_t)Dm + gj] =
            0.5f * (acc[fi][fj][r] * invN) - (gi == gj ? 0.5f : 0.0f);
      }
    }
}

// ---------------- small utility kernels -------------------------------------
__global__ void zero_f32(float* __restrict__ p, int n) {
  int i = blockIdx.x * blockDim.x + threadIdx.x;
  if (i < n) p[i] = 0.f;
}

__global__ void cvt_f32_bf16(const float* __restrict__ in, ushortT* __restrict__ out,
                             size_t n4) {
  size_t i = (size_t)blockIdx.x * blockDim.x + threadIdx.x;
  const size_t stride = (size_t)gridDim.x * blockDim.x;
  const f32x4* in4 = (const f32x4*)in;
  for (; i < n4; i += stride) {
    f32x4 v = __builtin_nontemporal_load(&in4[i]);
    us4 o = { f2bf(v.x), f2bf(v.y), f2bf(v.z), f2bf(v.w) };
    *(us4*)(out + i * 4) = o;
  }
}

__global__ void transposeQ(const float* __restrict__ q, ushortT* __restrict__ qT) {
  const int g = blockIdx.x * 256 + threadIdx.x;  // 131072 threads
  const int d = g >> 7;
  const int k0 = (g & 127) << 3;
  short8 v;
#pragma unroll
  for (int j = 0; j < 8; ++j) v[j] = (short)f2bf(q[(size_t)(k0 + j) * 1024 + d]);
  *(short8*)(qT + (size_t)d * 1024 + k0) = v;
}

__global__ void make_p(const float* __restrict__ q, ushortT* __restrict__ p) {
  const int g = blockIdx.x * 256 + threadIdx.x;  // 131072 threads
  const size_t base = (size_t)g * 8;
  const int e = (int)(base >> 10);
  const int d0 = (int)(base & 1023);
  short8 v;
#pragma unroll
  for (int j = 0; j < 8; ++j) {
    float f = q[base + j] - ((e == d0 + j) ? 1.0f : 0.0f);
    v[j] = (short)f2bf(f);
  }
  *(short8*)(p + base) = v;
}

__global__ void gather_rows(const float* __restrict__ x, const int* __restrict__ idx,
                            float* __restrict__ self32, ushortT* __restrict__ selbf) {
  const int bid = blockIdx.x;  // 0..8191
  const int b = bid >> 10;
  const int row = idx[bid] & 4095;  // harness passes int32; clamp for safety
  const float4* src = (const float4*)(x + ((size_t)b * 4096 + (size_t)row) * 1024);
  const int t = threadIdx.x;  // 256 threads * 4 floats = 1024
  float4 v = src[t];
  *(float4*)(self32 + (size_t)bid * 1024 + t * 4) = v;
  us4 o = { f2bf(v.x), f2bf(v.y), f2bf(v.z), f2bf(v.w) };
  *(us4*)(selbf + (size_t)bid * 1024 + t * 4) = o;
}

__global__ void loss_final(const float* __restrict__ S2, const float* __restrict__ S4,
                           float* __restrict__ out) {
  __shared__ double red0[256];
  __shared__ double red1[256];
  const int t = threadIdx.x;
  double ca = 0.0, wa = 0.0;
  for (int i = t; i < 8192; i += 256) {
    double s2 = (double)S2[i], s4 = (double)S4[i];
    ca += s2 * s2 - s4;
    wa += s4 - 2.0 * s2 + 1024.0;
  }
  red0[t] = ca; red1[t] = wa;
  __syncthreads();
  for (int s = 128; s > 0; s >>= 1) {
    if (t < s) { red0[t] += red0[t + s]; red1[t] += red1[t + s]; }
    __syncthreads();
  }
  if (t == 0) {
    const double inv = 1.0 / (8192.0 * 1024.0 * 1024.0);
    out[0] = (float)(red0[0] * inv);
    out[1] = (float)(red1[0] * inv);
  }
}

// ---------------- launch -----------------------------------------------------
extern "C" void kernel_launch(void* const* d_in, const int* in_sizes, int n_in,
                              void* d_out, int out_size, void* d_ws, size_t ws_size,
                              hipStream_t stream) {
  (void)in_sizes; (void)n_in; (void)out_size;
  const float* x = (const float*)d_in[0];       // (8,4096,1024) f32
  const float* weight = (const float*)d_in[1];  // (2048,1024) f32
  const float* bias = (const float*)d_in[2];    // (2048,) f32
  const float* decorr = (const float*)d_in[3];  // (1024,1024) f32
  const int* sidx = (const int*)d_in[4];        // (8,1024) int32

  if (ws_size < 146866176ULL) return;  // need ~140 MiB scratch

  char* ws = (char*)d_ws;
  ushortT* xbf     = (ushortT*)(ws);              // 33,554,432 bf16
  ushortT* fusedbf = (ushortT*)(ws + 67108864);   //  2,097,152 bf16
  ushortT* wbf     = (ushortT*)(ws + 71303168);   //  2,097,152 bf16
  ushortT* qT      = (ushortT*)(ws + 75497472);   //  1,048,576 bf16
  ushortT* pbf     = (ushortT*)(ws + 77594624);   //  1,048,576 bf16
  float*   self32  = (float*)  (ws + 79691776);   //  8,388,608 f32
  ushortT* selbf   = (ushortT*)(ws + 113246208);  //  8,388,608 bf16
  ushortT* sdT     = (ushortT*)(ws + 130023424);  //  8,388,608 bf16 (1024 x 8192)
  float*   S2      = (float*)  (ws + 146800640);  //  8192 f32
  float*   S4      = (float*)  (ws + 146833408);  //  8192 f32

  float* y = (float*)d_out;                          // 8*4096*2048
  float* grad = y + 67108864ULL;                     // 1024*1024
  float* losses = grad + 1048576ULL;                 // 2 scalars

  zero_f32<<<dim3(64), dim3(256), 0, stream>>>(S2, 16384);  // S2+S4 contiguous
  cvt_f32_bf16<<<dim3(2048), dim3(256), 0, stream>>>(x, xbf, 8388608);
  cvt_f32_bf16<<<dim3(512), dim3(256), 0, stream>>>(weight, wbf, 524288);
  transposeQ<<<dim3(512), dim3(256), 0, stream>>>(decorr, qT);
  make_p<<<dim3(512), dim3(256), 0, stream>>>(decorr, pbf);
  gather_rows<<<dim3(8192), dim3(256), 0, stream>>>(x, sidx, self32, selbf);

  // fused = W @ Q  ->  bf16 (A=wbf 2048xK, B=qT 1024xK)
  gemm128<1><<<dim3(16, 8), dim3(256), 0, stream>>>(
      wbf, qT, 2048, 1024, 1024, nullptr, fusedbf, nullptr, nullptr,
      nullptr, nullptr, nullptr, 0);
  // y = x @ fused^T + bias  — 256^2 depth-3 counted-vmcnt, LLC-friendly order
  gemm256<<<dim3(1024), dim3(512), 0, stream>>>(
      xbf, fusedbf, 32768, 2048, 1024, y, bias);
  // sd = sel + sel @ P^T; S2/S4 row sums; sdT transposed bf16
  gemm128<2><<<dim3(64, 8), dim3(256), 0, stream>>>(
      selbf, pbf, 8192, 1024, 1024, nullptr, nullptr, nullptr, self32,
      S2, S4, sdT, 8192);
  // grad = 0.5 * (sdT sdT^T)/N - 0.5 I
  mgemm64<<<dim3(16, 16), dim3(256), 0, stream>>>(sdT, 1024, 8192, grad,
                                                  1.0f / 8192.0f);
  loss_final<<<dim3(1), dim3(256), 0, stream>>>(S2, S4, losses);
}

// Round 7
// 379.694 us; speedup vs baseline: 1.2076x; 1.0495x over previous
//
#include <hip/hip_runtime.h>
#include <hip/hip_bf16.h>
#include <cstdint>

typedef unsigned short ushortT;
typedef __attribute__((ext_vector_type(8))) short short8;
typedef __attribute__((ext_vector_type(4))) float f32x4;
typedef __attribute__((ext_vector_type(4))) unsigned short us4;

__device__ __forceinline__ ushortT f2bf(float f) {
  union { float f; unsigned u; } v; v.f = f;
  unsigned r = (v.u + 0x7FFFu + ((v.u >> 16) & 1u)) >> 16;
  return (ushortT)r;
}

__device__ __forceinline__ void gl_lds16(const void* g, void* l) {
  __builtin_amdgcn_global_load_lds(
      (__attribute__((address_space(1))) void*)g,
      (__attribute__((address_space(3))) void*)l, 16, 0, 0);
}

// ============ 256x128 tile, 8-wave, 2 blocks/CU, counted-vmcnt GEMM ==========
// C = A @ B^T + bias. BK=32, 3 LDS buffers (72 KiB) -> 2 blocks/CU (TLP).
// 4M x 2N waves, 64x64 per wave (acc = 64 VGPR), __launch_bounds__(512,4).
// One vmcnt(3)+barrier per K-step; 2 tiles always in flight (never drain).
// mod-3 buffering is race-free: stage(kt+2) overwrites buf read at iter kt-1,
// whose reads completed before this iter's barrier.
__global__ __launch_bounds__(512, 4) void gemm256(
    const ushortT* __restrict__ A, const ushortT* __restrict__ B,
    int M, int N, int K,
    float* __restrict__ outF, const float* __restrict__ bias)
{
  __shared__ ushortT smem[3 * 256 * 32 + 3 * 128 * 32];  // 72 KiB
  ushortT(*sA)[256 * 32] = (ushortT(*)[256 * 32])smem;
  ushortT(*sB)[128 * 32] = (ushortT(*)[128 * 32])(smem + 3 * 256 * 32);

  const int tid = threadIdx.x;
  const int wv = tid >> 6, l = tid & 63;
  const int wm = wv >> 1, wn = wv & 1;  // 4M x 2N wave grid

  // XCD swizzle: xcd owns 16 contiguous m-panels; n varies slowly.
  const int bid = blockIdx.x;
  const int xcd = bid & 7, i = bid >> 3;        // i in [0,256)
  const int m0 = (xcd * 16 + (i & 15)) * 256;   // 128 m-panels
  const int n0 = (i >> 4) * 128;                // 16 n-panels
  const int NK = K >> 5;

  f32x4 acc[4][4] = {};

  const ushortT* Ab = A + (size_t)m0 * (size_t)K;
  const ushortT* Bb = B + (size_t)n0 * (size_t)K;

  const int sr = tid >> 2;                 // staging row 0..127
  const int sg = tid & 3;                  // staging granule
  const int gsw = sg ^ ((sr >> 1) & 3);    // inverse-swizzled source granule

  // stage one 256x32 A-tile (2 quarters) + 128x32 B-tile (1 quarter)
  auto stage = [&](int kt) {
    const int b = kt % 3;
    const size_t kof = (size_t)((kt << 5) + (gsw << 3));
    gl_lds16(Ab + (size_t)sr * (size_t)K + kof,         &sA[b][(wv * 16) * 32]);
    gl_lds16(Ab + (size_t)(128 + sr) * (size_t)K + kof, &sA[b][(128 + wv * 16) * 32]);
    gl_lds16(Bb + (size_t)sr * (size_t)K + kof,         &sB[b][(wv * 16) * 32]);
  };

  const int fr = l & 15;
  const int colsw = (((l >> 4) ^ ((fr >> 1) & 3)) << 3);  // swizzled read granule

  stage(0);
  stage(1);

  for (int kt = 0; kt < NK; ++kt) {
    if (kt + 1 < NK) asm volatile("s_waitcnt vmcnt(3)" ::: "memory");
    else             asm volatile("s_waitcnt vmcnt(0)" ::: "memory");
    __builtin_amdgcn_s_barrier();
    if (kt + 2 < NK) stage(kt + 2);

    const int bc = kt % 3;
    short8 av[4], bv8[4];
#pragma unroll
    for (int fi = 0; fi < 4; ++fi)
      av[fi] = *(const short8*)&sA[bc][(wm * 64 + fi * 16 + fr) * 32 + colsw];
#pragma unroll
    for (int fj = 0; fj < 4; ++fj)
      bv8[fj] = *(const short8*)&sB[bc][(wn * 64 + fj * 16 + fr) * 32 + colsw];

    __builtin_amdgcn_s_setprio(1);
#pragma unroll
    for (int fi = 0; fi < 4; ++fi)
#pragma unroll
      for (int fj = 0; fj < 4; ++fj)
        acc[fi][fj] = __builtin_amdgcn_mfma_f32_16x16x32_bf16(
            av[fi], bv8[fj], acc[fi][fj], 0, 0, 0);
    __builtin_amdgcn_s_setprio(0);
  }

  // ---- epilogue: LDS transpose (padded stride) -> contiguous nt stores ----
  const int cc = l & 15, r4 = (l >> 4) * 4;
  float bvv[4];
#pragma unroll
  for (int fj = 0; fj < 4; ++fj) bvv[fj] = bias[n0 + wn * 64 + fj * 16 + cc];

  float* lbuf = (float*)smem;  // 128 rows x 132 stride f32 = 67.6 KiB
#pragma unroll
  for (int s = 0; s < 2; ++s) {
    __syncthreads();
    if ((wm >> 1) == s) {
#pragma unroll
      for (int fi = 0; fi < 4; ++fi)
#pragma unroll
        for (int r = 0; r < 4; ++r) {
          const int row = (wm & 1) * 64 + fi * 16 + r4 + r;
#pragma unroll
          for (int fj = 0; fj < 4; ++fj)
            lbuf[row * 132 + wn * 64 + fj * 16 + cc] = acc[fi][fj][r] + bvv[fj];
        }
    }
    __syncthreads();
#pragma unroll
    for (int k = 0; k < 8; ++k) {
      const int f = k * 512 + tid;     // f32x4 index in 128x128 swath
      const int row = f >> 5, c4 = f & 31;
      f32x4 v = *(const f32x4*)&lbuf[row * 132 + c4 * 4];
      __builtin_nontemporal_store(
          v, (f32x4*)&outF[(size_t)(m0 + s * 128 + row) * (size_t)N + n0 + c4 * 4]);
    }
  }
}

// ---------------- 128x128 tile GEMM, C = A @ B^T, bf16 in, BK=32 -------------
template <int EPI>
__global__ __launch_bounds__(256) void gemm128(
    const ushortT* __restrict__ A, const ushortT* __restrict__ B,
    int M, int N, int K,
    float* __restrict__ outF, ushortT* __restrict__ outBF,
    const float* __restrict__ bias,
    const float* __restrict__ addend,
    float* __restrict__ S2, float* __restrict__ S4,
    ushortT* __restrict__ sdT, int ldT)
{
  __shared__ ushortT sA[2][128 * 32];
  __shared__ ushortT sB[2][128 * 32];
  const int tid = threadIdx.x;
  const int w = tid >> 6, l = tid & 63;
  const int wr = w >> 1, wc = w & 1;
  const int m0 = blockIdx.x * 128, n0 = blockIdx.y * 128;
  const int NK = K >> 5;

  f32x4 acc[4][4] = {};

  auto stage = [&](int buf, int kt) {
    const int k0 = kt << 5;
    const size_t colA = (size_t)(k0 + (l & 3) * 8);
    const int rb = w * 16 + (l >> 2);
#pragma unroll
    for (int c = 0; c < 2; ++c) {
      gl_lds16(A + (size_t)(m0 + c * 64 + rb) * (size_t)K + colA,
               &sA[buf][c * 2048 + w * 512]);
      gl_lds16(B + (size_t)(n0 + c * 64 + rb) * (size_t)K + colA,
               &sB[buf][c * 2048 + w * 512]);
    }
  };

  stage(0, 0);
  __syncthreads();

  for (int kt = 0; kt < NK; ++kt) {
    const int buf = kt & 1;
    if (kt + 1 < NK) stage(buf ^ 1, kt + 1);
    const int ro = (l & 15) * 32 + (l >> 4) * 8;
    short8 a[4], b[4];
#pragma unroll
    for (int f = 0; f < 4; ++f) {
      a[f] = *(const short8*)&sA[buf][(wr * 64 + f * 16) * 32 + ro];
      b[f] = *(const short8*)&sB[buf][(wc * 64 + f * 16) * 32 + ro];
    }
#pragma unroll
    for (int fi = 0; fi < 4; ++fi)
#pragma unroll
      for (int fj = 0; fj < 4; ++fj)
        acc[fi][fj] = __builtin_amdgcn_mfma_f32_16x16x32_bf16(
            a[fi], b[fj], acc[fi][fj], 0, 0, 0);
    __syncthreads();
  }

  const int r4 = (l >> 4) * 4, cc = l & 15;

  if constexpr (EPI == 0) {
#pragma unroll
    for (int fi = 0; fi < 4; ++fi)
#pragma unroll
      for (int r = 0; r < 4; ++r) {
        const size_t gm = (size_t)(m0 + wr * 64 + fi * 16 + r4 + r);
#pragma unroll
        for (int fj = 0; fj < 4; ++fj) {
          const int gn = n0 + wc * 64 + fj * 16 + cc;
          outF[gm * (size_t)N + gn] = acc[fi][fj][r] + bias[gn];
        }
      }
  } else if constexpr (EPI == 1) {
#pragma unroll
    for (int fi = 0; fi < 4; ++fi)
#pragma unroll
      for (int r = 0; r < 4; ++r) {
        const size_t gm = (size_t)(m0 + wr * 64 + fi * 16 + r4 + r);
#pragma unroll
        for (int fj = 0; fj < 4; ++fj) {
          const int gn = n0 + wc * 64 + fj * 16 + cc;
          outBF[gm * (size_t)N + gn] = f2bf(acc[fi][fj][r]);
        }
      }
  } else {
    __shared__ ushortT tbuf[128 * 136];
#pragma unroll
    for (int fi = 0; fi < 4; ++fi)
#pragma unroll
      for (int r = 0; r < 4; ++r) {
        const int row = wr * 64 + fi * 16 + r4 + r;
        const size_t gm = (size_t)(m0 + row);
        float rs2 = 0.f, rs4 = 0.f;
#pragma unroll
        for (int fj = 0; fj < 4; ++fj) {
          const int col = wc * 64 + fj * 16 + cc;
          float sd = acc[fi][fj][r] + addend[gm * (size_t)N + n0 + col];
          tbuf[col * 136 + row] = f2bf(sd);
          float s2 = sd * sd;
          rs2 += s2;
          rs4 += s2 * s2;
        }
#pragma unroll
        for (int mk = 1; mk < 16; mk <<= 1) {
          rs2 += __shfl_xor(rs2, mk, 16);
          rs4 += __shfl_xor(rs4, mk, 16);
        }
        if (cc == 0) { atomicAdd(&S2[gm], rs2); atomicAdd(&S4[gm], rs4); }
      }
    __syncthreads();
#pragma unroll
    for (int i = 0; i < 8; ++i) {
      const int er = i * 16 + (tid >> 4);
      const int nc = (tid & 15) * 8;
      short8 v = *(const short8*)&tbuf[er * 136 + nc];
      *(short8*)&sdT[(size_t)(n0 + er) * (size_t)ldT + m0 + nc] = v;
    }
  }
}

// ---------------- 64x64 tile GEMM for M = sdT @ sdT^T, writes grad ----------
__global__ __launch_bounds__(256) void mgemm64(
    const ushortT* __restrict__ T, int Dm, int K,
    float* __restrict__ grad, float invN)
{
  __shared__ ushortT sA[2][64 * 32];
  __shared__ ushortT sB[2][64 * 32];
  const int tid = threadIdx.x, w = tid >> 6, l = tid & 63;
  const int wr = w >> 1, wc = w & 1;
  const int i0 = blockIdx.x * 64, j0 = blockIdx.y * 64;
  const int NK = K >> 5;
  f32x4 acc[2][2] = {};

  auto stage = [&](int buf, int kt) {
    const int k0 = kt << 5;
    const size_t col = (size_t)(k0 + (l & 3) * 8);
    const int rb = w * 16 + (l >> 2);
    gl_lds16(T + (size_t)(i0 + rb) * (size_t)K + col, &sA[buf][w * 512]);
    gl_lds16(T + (size_t)(j0 + rb) * (size_t)K + col, &sB[buf][w * 512]);
  };

  stage(0, 0);
  __syncthreads();

  for (int kt = 0; kt < NK; ++kt) {
    const int buf = kt & 1;
    if (kt + 1 < NK) stage(buf ^ 1, kt + 1);
    const int ro = (l & 15) * 32 + (l >> 4) * 8;
    short8 a[2], b[2];
#pragma unroll
    for (int f = 0; f < 2; ++f) {
      a[f] = *(const short8*)&sA[buf][(wr * 32 + f * 16) * 32 + ro];
      b[f] = *(const short8*)&sB[buf][(wc * 32 + f * 16) * 32 + ro];
    }
#pragma unroll
    for (int fi = 0; fi < 2; ++fi)
#pragma unroll
      for (int fj = 0; fj < 2; ++fj)
        acc[fi][fj] = __builtin_amdgcn_mfma_f32_16x16x32_bf16(
            a[fi], b[fj], acc[fi][fj], 0, 0, 0);
    __syncthreads();
  }

  const int r4 = (l >> 4) * 4, cc = l & 15;
#pragma unroll
  for (int fi = 0; fi < 2; ++fi)
#pragma unroll
    for (int r = 0; r < 4; ++r) {
      const int gi = i0 + wr * 32 + fi * 16 + r4 + r;
#pragma unroll
      for (int fj = 0; fj < 2; ++fj) {
        const int gj = j0 + wc * 32 + fj * 16 + cc;
        grad[(size_t)gi * (size_t)Dm + gj] =
            0.5f * (acc[fi][fj][r] * invN) - (gi == gj ? 0.5f : 0.0f);
      }
    }
}

// ---------------- small utility kernels -------------------------------------
__global__ void zero_f32(float* __restrict__ p, int n) {
  int i = blockIdx.x * blockDim.x + threadIdx.x;
  if (i < n) p[i] = 0.f;
}

__global__ void cvt_f32_bf16(const float* __restrict__ in, ushortT* __restrict__ out,
                             size_t n4) {
  size_t i = (size_t)blockIdx.x * blockDim.x + threadIdx.x;
  const size_t stride = (size_t)gridDim.x * blockDim.x;
  const f32x4* in4 = (const f32x4*)in;
  for (; i < n4; i += stride) {
    f32x4 v = __builtin_nontemporal_load(&in4[i]);
    us4 o = { f2bf(v.x), f2bf(v.y), f2bf(v.z), f2bf(v.w) };
    *(us4*)(out + i * 4) = o;
  }
}

__global__ void transposeQ(const float* __restrict__ q, ushortT* __restrict__ qT) {
  const int g = blockIdx.x * 256 + threadIdx.x;  // 131072 threads
  const int d = g >> 7;
  const int k0 = (g & 127) << 3;
  short8 v;
#pragma unroll
  for (int j = 0; j < 8; ++j) v[j] = (short)f2bf(q[(size_t)(k0 + j) * 1024 + d]);
  *(short8*)(qT + (size_t)d * 1024 + k0) = v;
}

__global__ void make_p(const float* __restrict__ q, ushortT* __restrict__ p) {
  const int g = blockIdx.x * 256 + threadIdx.x;  // 131072 threads
  const size_t base = (size_t)g * 8;
  const int e = (int)(base >> 10);
  const int d0 = (int)(base & 1023);
  short8 v;
#pragma unroll
  for (int j = 0; j < 8; ++j) {
    float f = q[base + j] - ((e == d0 + j) ? 1.0f : 0.0f);
    v[j] = (short)f2bf(f);
  }
  *(short8*)(p + base) = v;
}

__global__ void gather_rows(const float* __restrict__ x, const int* __restrict__ idx,
                            float* __restrict__ self32, ushortT* __restrict__ selbf) {
  const int bid = blockIdx.x;  // 0..8191
  const int b = bid >> 10;
  const int row = idx[bid] & 4095;  // harness passes int32; clamp for safety
  const float4* src = (const float4*)(x + ((size_t)b * 4096 + (size_t)row) * 1024);
  const int t = threadIdx.x;  // 256 threads * 4 floats = 1024
  float4 v = src[t];
  *(float4*)(self32 + (size_t)bid * 1024 + t * 4) = v;
  us4 o = { f2bf(v.x), f2bf(v.y), f2bf(v.z), f2bf(v.w) };
  *(us4*)(selbf + (size_t)bid * 1024 + t * 4) = o;
}

__global__ void loss_final(const float* __restrict__ S2, const float* __restrict__ S4,
                           float* __restrict__ out) {
  __shared__ double red0[256];
  __shared__ double red1[256];
  const int t = threadIdx.x;
  double ca = 0.0, wa = 0.0;
  for (int i = t; i < 8192; i += 256) {
    double s2 = (double)S2[i], s4 = (double)S4[i];
    ca += s2 * s2 - s4;
    wa += s4 - 2.0 * s2 + 1024.0;
  }
  red0[t] = ca; red1[t] = wa;
  __syncthreads();
  for (int s = 128; s > 0; s >>= 1) {
    if (t < s) { red0[t] += red0[t + s]; red1[t] += red1[t + s]; }
    __syncthreads();
  }
  if (t == 0) {
    const double inv = 1.0 / (8192.0 * 1024.0 * 1024.0);
    out[0] = (float)(red0[0] * inv);
    out[1] = (float)(red1[0] * inv);
  }
}

// ---------------- launch -----------------------------------------------------
extern "C" void kernel_launch(void* const* d_in, const int* in_sizes, int n_in,
                              void* d_out, int out_size, void* d_ws, size_t ws_size,
                              hipStream_t stream) {
  (void)in_sizes; (void)n_in; (void)out_size;
  const float* x = (const float*)d_in[0];       // (8,4096,1024) f32
  const float* weight = (const float*)d_in[1];  // (2048,1024) f32
  const float* bias = (const float*)d_in[2];    // (2048,) f32
  const float* decorr = (const float*)d_in[3];  // (1024,1024) f32
  const int* sidx = (const int*)d_in[4];        // (8,1024) int32

  if (ws_size < 146866176ULL) return;  // need ~140 MiB scratch

  char* ws = (char*)d_ws;
  ushortT* xbf     = (ushortT*)(ws);              // 33,554,432 bf16
  ushortT* fusedbf = (ushortT*)(ws + 67108864);   //  2,097,152 bf16
  ushortT* wbf     = (ushortT*)(ws + 71303168);   //  2,097,152 bf16
  ushortT* qT      = (ushortT*)(ws + 75497472);   //  1,048,576 bf16
  ushortT* pbf     = (ushortT*)(ws + 77594624);   //  1,048,576 bf16
  float*   self32  = (float*)  (ws + 79691776);   //  8,388,608 f32
  ushortT* selbf   = (ushortT*)(ws + 113246208);  //  8,388,608 bf16
  ushortT* sdT     = (ushortT*)(ws + 130023424);  //  8,388,608 bf16 (1024 x 8192)
  float*   S2      = (float*)  (ws + 146800640);  //  8192 f32
  float*   S4      = (float*)  (ws + 146833408);  //  8192 f32

  float* y = (float*)d_out;                          // 8*4096*2048
  float* grad = y + 67108864ULL;                     // 1024*1024
  float* losses = grad + 1048576ULL;                 // 2 scalars

  zero_f32<<<dim3(64), dim3(256), 0, stream>>>(S2, 16384);  // S2+S4 contiguous
  cvt_f32_bf16<<<dim3(2048), dim3(256), 0, stream>>>(x, xbf, 8388608);
  cvt_f32_bf16<<<dim3(512), dim3(256), 0, stream>>>(weight, wbf, 524288);
  transposeQ<<<dim3(512), dim3(256), 0, stream>>>(decorr, qT);
  make_p<<<dim3(512), dim3(256), 0, stream>>>(decorr, pbf);
  gather_rows<<<dim3(8192), dim3(256), 0, stream>>>(x, sidx, self32, selbf);

  // fused = W @ Q  ->  bf16 (A=wbf 2048xK, B=qT 1024xK)
  gemm128<1><<<dim3(16, 8), dim3(256), 0, stream>>>(
      wbf, qT, 2048, 1024, 1024, nullptr, fusedbf, nullptr, nullptr,
      nullptr, nullptr, nullptr, 0);
  // y = x @ fused^T + bias  — 256x128 tile, 2 blocks/CU, counted vmcnt
  gemm256<<<dim3(2048), dim3(512), 0, stream>>>(
      xbf, fusedbf, 32768, 2048, 1024, y, bias);
  // sd = sel + sel @ P^T; S2/S4 row sums; sdT transposed bf16
  gemm128<2><<<dim3(64, 8), dim3(256), 0, stream>>>(
      selbf, pbf, 8192, 1024, 1024, nullptr, nullptr, nullptr, self32,
      S2, S4, sdT, 8192);
  // grad = 0.5 * (sdT sdT^T)/N - 0.5 I
  mgemm64<<<dim3(16, 16), dim3(256), 0, stream>>>(sdT, 1024, 8192, grad,
                                                  1.0f / 8192.0f);
  loss_final<<<dim3(1), dim3(256), 0, stream>>>(S2, S4, losses);
}

// Round 8
// 326.300 us; speedup vs baseline: 1.4053x; 1.1636x over previous
//
#include <hip/hip_runtime.h>
#include <hip/hip_bf16.h>
#include <cstdint>

typedef unsigned short ushortT;
typedef __attribute__((ext_vector_type(8))) short short8;
typedef __attribute__((ext_vector_type(4))) float f32x4;
typedef __attribute__((ext_vector_type(4))) unsigned short us4;

__device__ __forceinline__ ushortT f2bf(float f) {
  union { float f; unsigned u; } v; v.f = f;
  unsigned r = (v.u + 0x7FFFu + ((v.u >> 16) & 1u)) >> 16;
  return (ushortT)r;
}

__device__ __forceinline__ void gl_lds16(const void* g, void* l) {
  __builtin_amdgcn_global_load_lds(
      (__attribute__((address_space(1))) void*)g,
      (__attribute__((address_space(3))) void*)l, 16, 0, 0);
}

// ============ 256x128 tile, 8-wave, 2 blocks/CU, counted-vmcnt GEMM ==========
// C = A @ B^T + bias. BK=32, 3 LDS buffers (72 KiB) -> 2 blocks/CU (TLP).
// XCD swizzle: n fast, m slow -> concurrent set/XCD = 4 m-panels x 16 n-panels
// (A ws 2 MB + B 4 MB ~ L2-resident; A fetched ~once from HBM).
__global__ __launch_bounds__(512, 4) void gemm256(
    const ushortT* __restrict__ A, const ushortT* __restrict__ B,
    int M, int N, int K,
    float* __restrict__ outF, const float* __restrict__ bias)
{
  __shared__ ushortT smem[3 * 256 * 32 + 3 * 128 * 32];  // 72 KiB
  ushortT(*sA)[256 * 32] = (ushortT(*)[256 * 32])smem;
  ushortT(*sB)[128 * 32] = (ushortT(*)[128 * 32])(smem + 3 * 256 * 32);

  const int tid = threadIdx.x;
  const int wv = tid >> 6, l = tid & 63;
  const int wm = wv >> 1, wn = wv & 1;  // 4M x 2N wave grid

  // XCD swizzle: xcd owns 16 contiguous m-panels; n varies FAST.
  const int bid = blockIdx.x;
  const int xcd = bid & 7, i = bid >> 3;        // i in [0,256)
  const int n0 = (i & 15) * 128;                // 16 n-panels (fast)
  const int m0 = (xcd * 16 + (i >> 4)) * 256;   // 128 m-panels (slow)
  const int NK = K >> 5;

  f32x4 acc[4][4] = {};

  const ushortT* Ab = A + (size_t)m0 * (size_t)K;
  const ushortT* Bb = B + (size_t)n0 * (size_t)K;

  const int sr = tid >> 2;                 // staging row 0..127
  const int sg = tid & 3;                  // staging granule
  const int gsw = sg ^ ((sr >> 1) & 3);    // inverse-swizzled source granule

  auto stage = [&](int kt) {
    const int b = kt % 3;
    const size_t kof = (size_t)((kt << 5) + (gsw << 3));
    gl_lds16(Ab + (size_t)sr * (size_t)K + kof,         &sA[b][(wv * 16) * 32]);
    gl_lds16(Ab + (size_t)(128 + sr) * (size_t)K + kof, &sA[b][(128 + wv * 16) * 32]);
    gl_lds16(Bb + (size_t)sr * (size_t)K + kof,         &sB[b][(wv * 16) * 32]);
  };

  const int fr = l & 15;
  const int colsw = (((l >> 4) ^ ((fr >> 1) & 3)) << 3);  // swizzled read granule

  stage(0);
  stage(1);

  for (int kt = 0; kt < NK; ++kt) {
    if (kt + 1 < NK) asm volatile("s_waitcnt vmcnt(3)" ::: "memory");
    else             asm volatile("s_waitcnt vmcnt(0)" ::: "memory");
    __builtin_amdgcn_s_barrier();
    if (kt + 2 < NK) stage(kt + 2);

    const int bc = kt % 3;
    short8 av[4], bv8[4];
#pragma unroll
    for (int fi = 0; fi < 4; ++fi)
      av[fi] = *(const short8*)&sA[bc][(wm * 64 + fi * 16 + fr) * 32 + colsw];
#pragma unroll
    for (int fj = 0; fj < 4; ++fj)
      bv8[fj] = *(const short8*)&sB[bc][(wn * 64 + fj * 16 + fr) * 32 + colsw];

    __builtin_amdgcn_s_setprio(1);
#pragma unroll
    for (int fi = 0; fi < 4; ++fi)
#pragma unroll
      for (int fj = 0; fj < 4; ++fj)
        acc[fi][fj] = __builtin_amdgcn_mfma_f32_16x16x32_bf16(
            av[fi], bv8[fj], acc[fi][fj], 0, 0, 0);
    __builtin_amdgcn_s_setprio(0);
  }

  // ---- epilogue: LDS transpose (padded stride) -> contiguous nt stores ----
  const int cc = l & 15, r4 = (l >> 4) * 4;
  float bvv[4];
#pragma unroll
  for (int fj = 0; fj < 4; ++fj) bvv[fj] = bias[n0 + wn * 64 + fj * 16 + cc];

  float* lbuf = (float*)smem;  // 128 rows x 132 stride f32 = 67.6 KiB
#pragma unroll
  for (int s = 0; s < 2; ++s) {
    __syncthreads();
    if ((wm >> 1) == s) {
#pragma unroll
      for (int fi = 0; fi < 4; ++fi)
#pragma unroll
        for (int r = 0; r < 4; ++r) {
          const int row = (wm & 1) * 64 + fi * 16 + r4 + r;
#pragma unroll
          for (int fj = 0; fj < 4; ++fj)
            lbuf[row * 132 + wn * 64 + fj * 16 + cc] = acc[fi][fj][r] + bvv[fj];
        }
    }
    __syncthreads();
#pragma unroll
    for (int k = 0; k < 8; ++k) {
      const int f = k * 512 + tid;     // f32x4 index in 128x128 swath
      const int row = f >> 5, c4 = f & 31;
      f32x4 v = *(const f32x4*)&lbuf[row * 132 + c4 * 4];
      __builtin_nontemporal_store(
          v, (f32x4*)&outF[(size_t)(m0 + s * 128 + row) * (size_t)N + n0 + c4 * 4]);
    }
  }
}

// ---------------- 128x128 tile GEMM, C = A @ B^T, bf16 in, BK=32 -------------
template <int EPI>
__global__ __launch_bounds__(256) void gemm128(
    const ushortT* __restrict__ A, const ushortT* __restrict__ B,
    int M, int N, int K,
    float* __restrict__ outF, ushortT* __restrict__ outBF,
    const float* __restrict__ bias,
    const float* __restrict__ addend,
    float* __restrict__ S2, float* __restrict__ S4,
    ushortT* __restrict__ sdT, int ldT)
{
  __shared__ ushortT sA[2][128 * 32];
  __shared__ ushortT sB[2][128 * 32];
  const int tid = threadIdx.x;
  const int w = tid >> 6, l = tid & 63;
  const int wr = w >> 1, wc = w & 1;
  const int m0 = blockIdx.x * 128, n0 = blockIdx.y * 128;
  const int NK = K >> 5;

  f32x4 acc[4][4] = {};

  auto stage = [&](int buf, int kt) {
    const int k0 = kt << 5;
    const size_t colA = (size_t)(k0 + (l & 3) * 8);
    const int rb = w * 16 + (l >> 2);
#pragma unroll
    for (int c = 0; c < 2; ++c) {
      gl_lds16(A + (size_t)(m0 + c * 64 + rb) * (size_t)K + colA,
               &sA[buf][c * 2048 + w * 512]);
      gl_lds16(B + (size_t)(n0 + c * 64 + rb) * (size_t)K + colA,
               &sB[buf][c * 2048 + w * 512]);
    }
  };

  stage(0, 0);
  __syncthreads();

  for (int kt = 0; kt < NK; ++kt) {
    const int buf = kt & 1;
    if (kt + 1 < NK) stage(buf ^ 1, kt + 1);
    const int ro = (l & 15) * 32 + (l >> 4) * 8;
    short8 a[4], b[4];
#pragma unroll
    for (int f = 0; f < 4; ++f) {
      a[f] = *(const short8*)&sA[buf][(wr * 64 + f * 16) * 32 + ro];
      b[f] = *(const short8*)&sB[buf][(wc * 64 + f * 16) * 32 + ro];
    }
#pragma unroll
    for (int fi = 0; fi < 4; ++fi)
#pragma unroll
      for (int fj = 0; fj < 4; ++fj)
        acc[fi][fj] = __builtin_amdgcn_mfma_f32_16x16x32_bf16(
            a[fi], b[fj], acc[fi][fj], 0, 0, 0);
    __syncthreads();
  }

  const int r4 = (l >> 4) * 4, cc = l & 15;

  if constexpr (EPI == 1) {
#pragma unroll
    for (int fi = 0; fi < 4; ++fi)
#pragma unroll
      for (int r = 0; r < 4; ++r) {
        const size_t gm = (size_t)(m0 + wr * 64 + fi * 16 + r4 + r);
#pragma unroll
        for (int fj = 0; fj < 4; ++fj) {
          const int gn = n0 + wc * 64 + fj * 16 + cc;
          outBF[gm * (size_t)N + gn] = f2bf(acc[fi][fj][r]);
        }
      }
  } else {
    __shared__ ushortT tbuf[128 * 136];
#pragma unroll
    for (int fi = 0; fi < 4; ++fi)
#pragma unroll
      for (int r = 0; r < 4; ++r) {
        const int row = wr * 64 + fi * 16 + r4 + r;
        const size_t gm = (size_t)(m0 + row);
        float rs2 = 0.f, rs4 = 0.f;
#pragma unroll
        for (int fj = 0; fj < 4; ++fj) {
          const int col = wc * 64 + fj * 16 + cc;
          float sd = acc[fi][fj][r] + addend[gm * (size_t)N + n0 + col];
          tbuf[col * 136 + row] = f2bf(sd);
          float s2 = sd * sd;
          rs2 += s2;
          rs4 += s2 * s2;
        }
#pragma unroll
        for (int mk = 1; mk < 16; mk <<= 1) {
          rs2 += __shfl_xor(rs2, mk, 16);
          rs4 += __shfl_xor(rs4, mk, 16);
        }
        if (cc == 0) { atomicAdd(&S2[gm], rs2); atomicAdd(&S4[gm], rs4); }
      }
    __syncthreads();
#pragma unroll
    for (int i = 0; i < 8; ++i) {
      const int er = i * 16 + (tid >> 4);
      const int nc = (tid & 15) * 8;
      short8 v = *(const short8*)&tbuf[er * 136 + nc];
      *(short8*)&sdT[(size_t)(n0 + er) * (size_t)ldT + m0 + nc] = v;
    }
  }
}

// -------- 128x128 split-K GEMM for M = sdT sdT^T: partials, no scaling ------
// grid (8,8,4): z-chunk covers K rows [z*2048, (z+1)*2048). Writes f32
// partial[z][1024][1024].
__global__ __launch_bounds__(256) void mgemm128sk(
    const ushortT* __restrict__ T, int Dm, int K,
    float* __restrict__ pbuf)
{
  __shared__ ushortT sA[2][128 * 32];
  __shared__ ushortT sB[2][128 * 32];
  const int tid = threadIdx.x, w = tid >> 6, l = tid & 63;
  const int wr = w >> 1, wc = w & 1;
  const int i0 = blockIdx.x * 128, j0 = blockIdx.y * 128;
  const int kt0 = blockIdx.z * 64;  // 64 K-steps of 32 per chunk
  f32x4 acc[4][4] = {};

  auto stage = [&](int buf, int kt) {
    const int k0 = kt << 5;
    const size_t col = (size_t)(k0 + (l & 3) * 8);
    const int rb = w * 16 + (l >> 2);
#pragma unroll
    for (int c = 0; c < 2; ++c) {
      gl_lds16(T + (size_t)(i0 + c * 64 + rb) * (size_t)K + col,
               &sA[buf][c * 2048 + w * 512]);
      gl_lds16(T + (size_t)(j0 + c * 64 + rb) * (size_t)K + col,
               &sB[buf][c * 2048 + w * 512]);
    }
  };

  stage(0, kt0);
  __syncthreads();

  for (int t = 0; t < 64; ++t) {
    const int buf = t & 1;
    if (t + 1 < 64) stage(buf ^ 1, kt0 + t + 1);
    const int ro = (l & 15) * 32 + (l >> 4) * 8;
    short8 a[4], b[4];
#pragma unroll
    for (int f = 0; f < 4; ++f) {
      a[f] = *(const short8*)&sA[buf][(wr * 64 + f * 16) * 32 + ro];
      b[f] = *(const short8*)&sB[buf][(wc * 64 + f * 16) * 32 + ro];
    }
#pragma unroll
    for (int fi = 0; fi < 4; ++fi)
#pragma unroll
      for (int fj = 0; fj < 4; ++fj)
        acc[fi][fj] = __builtin_amdgcn_mfma_f32_16x16x32_bf16(
            a[fi], b[fj], acc[fi][fj], 0, 0, 0);
    __syncthreads();
  }

  const int r4 = (l >> 4) * 4, cc = l & 15;
  float* out = pbuf + ((size_t)blockIdx.z << 20);
#pragma unroll
  for (int fi = 0; fi < 4; ++fi)
#pragma unroll
    for (int r = 0; r < 4; ++r) {
      const int gi = i0 + wr * 64 + fi * 16 + r4 + r;
#pragma unroll
      for (int fj = 0; fj < 4; ++fj) {
        const int gj = j0 + wc * 64 + fj * 16 + cc;
        out[(size_t)gi * (size_t)Dm + gj] = acc[fi][fj][r];
      }
    }
}

__global__ void reduce_grad(const float* __restrict__ pbuf,
                            float* __restrict__ grad, float invN) {
  const int i = blockIdx.x * 256 + threadIdx.x;  // 262144 f32x4 groups
  const size_t base = (size_t)i * 4;
  f32x4 s = *(const f32x4*)(pbuf + base) + *(const f32x4*)(pbuf + base + (1u << 20)) +
            *(const f32x4*)(pbuf + base + (2u << 20)) + *(const f32x4*)(pbuf + base + (3u << 20));
  const int row = (int)(base >> 10), c0 = (int)(base & 1023);
  f32x4 o;
#pragma unroll
  for (int j = 0; j < 4; ++j)
    o[j] = 0.5f * (s[j] * invN) - ((row == c0 + j) ? 0.5f : 0.0f);
  *(f32x4*)(grad + base) = o;
}

// ---------------- small utility kernels -------------------------------------
__global__ void zero_f32(float* __restrict__ p, int n) {
  int i = blockIdx.x * blockDim.x + threadIdx.x;
  if (i < n) p[i] = 0.f;
}

__global__ void cvt_f32_bf16(const float* __restrict__ in, ushortT* __restrict__ out,
                             size_t n4) {
  size_t i = (size_t)blockIdx.x * blockDim.x + threadIdx.x;
  const size_t stride = (size_t)gridDim.x * blockDim.x;
  const f32x4* in4 = (const f32x4*)in;
  for (; i < n4; i += stride) {
    f32x4 v = __builtin_nontemporal_load(&in4[i]);
    us4 o = { f2bf(v.x), f2bf(v.y), f2bf(v.z), f2bf(v.w) };
    *(us4*)(out + i * 4) = o;
  }
}

// LDS-tiled coalesced transpose: qT[d][k] = bf16(q[k][d]). grid 8x8, 256 thr.
__global__ __launch_bounds__(256) void transposeQ(const float* __restrict__ q,
                                                  ushortT* __restrict__ qT) {
  __shared__ float t[128][129];
  const int bi = blockIdx.x, bj = blockIdx.y;  // k-tile, d-tile
  const int tr = threadIdx.x >> 5, tc = threadIdx.x & 31;
#pragma unroll
  for (int i = 0; i < 16; ++i) {
    const int row = i * 8 + tr;
    f32x4 v = *(const f32x4*)&q[(size_t)(bi * 128 + row) * 1024 + bj * 128 + tc * 4];
#pragma unroll
    for (int j = 0; j < 4; ++j) t[row][tc * 4 + j] = v[j];
  }
  __syncthreads();
#pragma unroll
  for (int i = 0; i < 16; ++i) {
    const int dr = i * 8 + tr;
    us4 o = { f2bf(t[tc * 4 + 0][dr]), f2bf(t[tc * 4 + 1][dr]),
              f2bf(t[tc * 4 + 2][dr]), f2bf(t[tc * 4 + 3][dr]) };
    *(us4*)&qT[(size_t)(bj * 128 + dr) * 1024 + bi * 128 + tc * 4] = o;
  }
}

__global__ void make_p(const float* __restrict__ q, ushortT* __restrict__ p) {
  const int g = blockIdx.x * 256 + threadIdx.x;  // 131072 threads
  const size_t base = (size_t)g * 8;
  const int e = (int)(base >> 10);
  const int d0 = (int)(base & 1023);
  short8 v;
#pragma unroll
  for (int j = 0; j < 8; ++j) {
    float f = q[base + j] - ((e == d0 + j) ? 1.0f : 0.0f);
    v[j] = (short)f2bf(f);
  }
  *(short8*)(p + base) = v;
}

__global__ void gather_rows(const float* __restrict__ x, const int* __restrict__ idx,
                            float* __restrict__ self32, ushortT* __restrict__ selbf) {
  const int bid = blockIdx.x;  // 0..8191
  const int b = bid >> 10;
  const int row = idx[bid] & 4095;
  const float4* src = (const float4*)(x + ((size_t)b * 4096 + (size_t)row) * 1024);
  const int t = threadIdx.x;
  float4 v = src[t];
  *(float4*)(self32 + (size_t)bid * 1024 + t * 4) = v;
  us4 o = { f2bf(v.x), f2bf(v.y), f2bf(v.z), f2bf(v.w) };
  *(us4*)(selbf + (size_t)bid * 1024 + t * 4) = o;
}

__global__ void loss_final(const float* __restrict__ S2, const float* __restrict__ S4,
                           float* __restrict__ out) {
  __shared__ double red0[256];
  __shared__ double red1[256];
  const int t = threadIdx.x;
  double ca = 0.0, wa = 0.0;
  for (int i = t; i < 8192; i += 256) {
    double s2 = (double)S2[i], s4 = (double)S4[i];
    ca += s2 * s2 - s4;
    wa += s4 - 2.0 * s2 + 1024.0;
  }
  red0[t] = ca; red1[t] = wa;
  __syncthreads();
  for (int s = 128; s > 0; s >>= 1) {
    if (t < s) { red0[t] += red0[t + s]; red1[t] += red1[t + s]; }
    __syncthreads();
  }
  if (t == 0) {
    const double inv = 1.0 / (8192.0 * 1024.0 * 1024.0);
    out[0] = (float)(red0[0] * inv);
    out[1] = (float)(red1[0] * inv);
  }
}

// ---------------- launch -----------------------------------------------------
extern "C" void kernel_launch(void* const* d_in, const int* in_sizes, int n_in,
                              void* d_out, int out_size, void* d_ws, size_t ws_size,
                              hipStream_t stream) {
  (void)in_sizes; (void)n_in; (void)out_size;
  const float* x = (const float*)d_in[0];       // (8,4096,1024) f32
  const float* weight = (const float*)d_in[1];  // (2048,1024) f32
  const float* bias = (const float*)d_in[2];    // (2048,) f32
  const float* decorr = (const float*)d_in[3];  // (1024,1024) f32
  const int* sidx = (const int*)d_in[4];        // (8,1024) int32

  if (ws_size < 146866176ULL) return;

  char* ws = (char*)d_ws;
  ushortT* xbf     = (ushortT*)(ws);              // 33,554,432 bf16
  ushortT* fusedbf = (ushortT*)(ws + 67108864);   //  2,097,152 bf16
  ushortT* wbf     = (ushortT*)(ws + 71303168);   //  2,097,152 bf16
  ushortT* qT      = (ushortT*)(ws + 75497472);   //  1,048,576 bf16
  ushortT* pbf     = (ushortT*)(ws + 77594624);   //  1,048,576 bf16
  float*   self32  = (float*)  (ws + 79691776);   //  8,388,608 f32 (also split-K partials)
  ushortT* selbf   = (ushortT*)(ws + 113246208);  //  8,388,608 bf16
  ushortT* sdT     = (ushortT*)(ws + 130023424);  //  8,388,608 bf16 (1024 x 8192)
  float*   S2      = (float*)  (ws + 146800640);  //  8192 f32
  float*   S4      = (float*)  (ws + 146833408);  //  8192 f32

  float* y = (float*)d_out;                          // 8*4096*2048
  float* grad = y + 67108864ULL;                     // 1024*1024
  float* losses = grad + 1048576ULL;                 // 2 scalars

  zero_f32<<<dim3(64), dim3(256), 0, stream>>>(S2, 16384);
  cvt_f32_bf16<<<dim3(2048), dim3(256), 0, stream>>>(x, xbf, 8388608);
  cvt_f32_bf16<<<dim3(512), dim3(256), 0, stream>>>(weight, wbf, 524288);
  transposeQ<<<dim3(8, 8), dim3(256), 0, stream>>>(decorr, qT);
  make_p<<<dim3(512), dim3(256), 0, stream>>>(decorr, pbf);
  gather_rows<<<dim3(8192), dim3(256), 0, stream>>>(x, sidx, self32, selbf);

  // fused = W @ Q  ->  bf16
  gemm128<1><<<dim3(16, 8), dim3(256), 0, stream>>>(
      wbf, qT, 2048, 1024, 1024, nullptr, fusedbf, nullptr, nullptr,
      nullptr, nullptr, nullptr, 0);
  // y = x @ fused^T + bias  — 256x128 tile, 2 blocks/CU, counted vmcnt
  gemm256<<<dim3(2048), dim3(512), 0, stream>>>(
      xbf, fusedbf, 32768, 2048, 1024, y, bias);
  // sd = sel + sel @ P^T; S2/S4 row sums; sdT transposed bf16
  gemm128<2><<<dim3(64, 8), dim3(256), 0, stream>>>(
      selbf, pbf, 8192, 1024, 1024, nullptr, nullptr, nullptr, self32,
      S2, S4, sdT, 8192);
  // M partials = sdT sdT^T (split-K x4, 128^2 tiles), then reduce to grad
  mgemm128sk<<<dim3(8, 8, 4), dim3(256), 0, stream>>>(sdT, 1024, 8192, self32);
  reduce_grad<<<dim3(1024), dim3(256), 0, stream>>>(self32, grad, 1.0f / 8192.0f);
  loss_final<<<dim3(1), dim3(256), 0, stream>>>(S2, S4, losses);
}

// Round 9
// 325.553 us; speedup vs baseline: 1.4085x; 1.0023x over previous
//
#include <hip/hip_runtime.h>
#include <hip/hip_bf16.h>
#include <cstdint>

typedef unsigned short ushortT;
typedef __attribute__((ext_vector_type(8))) short short8;
typedef __attribute__((ext_vector_type(4))) float f32x4;
typedef __attribute__((ext_vector_type(4))) unsigned short us4;

__device__ __forceinline__ ushortT f2bf(float f) {
  union { float f; unsigned u; } v; v.f = f;
  unsigned r = (v.u + 0x7FFFu + ((v.u >> 16) & 1u)) >> 16;
  return (ushortT)r;
}

__device__ __forceinline__ void gl_lds16(const void* g, void* l) {
  __builtin_amdgcn_global_load_lds(
      (__attribute__((address_space(1))) void*)g,
      (__attribute__((address_space(3))) void*)l, 16, 0, 0);
}

// ===== 256x128 tile, 4 waves (128x64/wave), 2 blocks/CU, counted vmcnt ======
// C = A @ B^T + bias. BK=32, 3 LDS buffers (72 KiB) -> 2 blocks/CU.
// Per-wave tile 128x64 -> 42.7 FLOP per LDS byte (vs 32 at 64x64): LDS pipe
// pressure drops 18%/CU and each wave runs 32 back-to-back MFMA.
// 6 gl_lds16 per thread per K-step; prefetch 2 ahead; vmcnt(6) retires the
// oldest K-step (never drains mid-loop). mod-3 buffering race-free as in r7.
__global__ __launch_bounds__(256, 2) void gemm256(
    const ushortT* __restrict__ A, const ushortT* __restrict__ B,
    int M, int N, int K,
    float* __restrict__ outF, const float* __restrict__ bias)
{
  __shared__ ushortT smem[3 * 256 * 32 + 3 * 128 * 32];  // 72 KiB
  ushortT(*sA)[256 * 32] = (ushortT(*)[256 * 32])smem;
  ushortT(*sB)[128 * 32] = (ushortT(*)[128 * 32])(smem + 3 * 256 * 32);

  const int tid = threadIdx.x;
  const int wv = tid >> 6, l = tid & 63;
  const int wm = wv >> 1, wn = wv & 1;  // 2M x 2N waves, 128x64 each

  // XCD swizzle: n fast, m slow (A+B working set ~L2-resident per XCD)
  const int bid = blockIdx.x;
  const int xcd = bid & 7, i = bid >> 3;
  const int n0 = (i & 15) * 128;
  const int m0 = (xcd * 16 + (i >> 4)) * 256;
  const int NK = K >> 5;

  f32x4 acc[8][4] = {};

  const ushortT* Ab = A + (size_t)m0 * (size_t)K;
  const ushortT* Bb = B + (size_t)n0 * (size_t)K;

  // staging: lane block covers 16 rows x 4 granules per wave-instruction
  const int lr = l >> 2;                   // 0..15 row within 16-row block
  const int sg = l & 3;                    // granule
  auto stage = [&](int kt) {
    const int b = kt % 3;
#pragma unroll
    for (int i2 = 0; i2 < 4; ++i2) {       // A: 4 x 64-row quarters
      const int r = i2 * 64 + wv * 16 + lr;
      const int gs = sg ^ ((r >> 1) & 3);
      gl_lds16(Ab + (size_t)r * (size_t)K + (size_t)((kt << 5) + (gs << 3)),
               &sA[b][(i2 * 64 + wv * 16) * 32]);
    }
#pragma unroll
    for (int i2 = 0; i2 < 2; ++i2) {       // B: 2 x 64-row quarters
      const int r = i2 * 64 + wv * 16 + lr;
      const int gs = sg ^ ((r >> 1) & 3);
      gl_lds16(Bb + (size_t)r * (size_t)K + (size_t)((kt << 5) + (gs << 3)),
               &sB[b][(i2 * 64 + wv * 16) * 32]);
    }
  };

  const int fr = l & 15;
  const int colsw = (((l >> 4) ^ ((fr >> 1) & 3)) << 3);  // swizzled read granule

  stage(0);
  stage(1);

  for (int kt = 0; kt < NK; ++kt) {
    if (kt + 1 < NK) asm volatile("s_waitcnt vmcnt(6)" ::: "memory");
    else             asm volatile("s_waitcnt vmcnt(0)" ::: "memory");
    __builtin_amdgcn_s_barrier();
    if (kt + 2 < NK) stage(kt + 2);

    const int bc = kt % 3;
    short8 av[8], bv8[4];
#pragma unroll
    for (int fi = 0; fi < 8; ++fi)
      av[fi] = *(const short8*)&sA[bc][(wm * 128 + fi * 16 + fr) * 32 + colsw];
#pragma unroll
    for (int fj = 0; fj < 4; ++fj)
      bv8[fj] = *(const short8*)&sB[bc][(wn * 64 + fj * 16 + fr) * 32 + colsw];

    __builtin_amdgcn_s_setprio(1);
#pragma unroll
    for (int fi = 0; fi < 8; ++fi)
#pragma unroll
      for (int fj = 0; fj < 4; ++fj)
        acc[fi][fj] = __builtin_amdgcn_mfma_f32_16x16x32_bf16(
            av[fi], bv8[fj], acc[fi][fj], 0, 0, 0);
    __builtin_amdgcn_s_setprio(0);
  }

  // ---- epilogue: LDS transpose (padded stride) -> contiguous nt stores ----
  const int cc = l & 15, r4 = (l >> 4) * 4;
  float bvv[4];
#pragma unroll
  for (int fj = 0; fj < 4; ++fj) bvv[fj] = bias[n0 + wn * 64 + fj * 16 + cc];

  float* lbuf = (float*)smem;  // 128 rows x 132 stride f32 = 67.6 KiB
#pragma unroll
  for (int s = 0; s < 2; ++s) {
    __syncthreads();
    if (wm == s) {
#pragma unroll
      for (int fi = 0; fi < 8; ++fi)
#pragma unroll
        for (int r = 0; r < 4; ++r) {
          const int row = fi * 16 + r4 + r;
#pragma unroll
          for (int fj = 0; fj < 4; ++fj)
            lbuf[row * 132 + wn * 64 + fj * 16 + cc] = acc[fi][fj][r] + bvv[fj];
        }
    }
    __syncthreads();
#pragma unroll
    for (int k = 0; k < 16; ++k) {
      const int f = k * 256 + tid;     // f32x4 index in 128x128 swath
      const int row = f >> 5, c4 = f & 31;
      f32x4 v = *(const f32x4*)&lbuf[row * 132 + c4 * 4];
      __builtin_nontemporal_store(
          v, (f32x4*)&outF[(size_t)(m0 + s * 128 + row) * (size_t)N + n0 + c4 * 4]);
    }
  }
}

// ---------------- 128x128 tile GEMM, C = A @ B^T, bf16 in, BK=32 -------------
template <int EPI>
__global__ __launch_bounds__(256) void gemm128(
    const ushortT* __restrict__ A, const ushortT* __restrict__ B,
    int M, int N, int K,
    float* __restrict__ outF, ushortT* __restrict__ outBF,
    const float* __restrict__ bias,
    const float* __restrict__ addend,
    float* __restrict__ S2, float* __restrict__ S4,
    ushortT* __restrict__ sdT, int ldT)
{
  __shared__ ushortT sA[2][128 * 32];
  __shared__ ushortT sB[2][128 * 32];
  const int tid = threadIdx.x;
  const int w = tid >> 6, l = tid & 63;
  const int wr = w >> 1, wc = w & 1;
  const int m0 = blockIdx.x * 128, n0 = blockIdx.y * 128;
  const int NK = K >> 5;

  f32x4 acc[4][4] = {};

  auto stage = [&](int buf, int kt) {
    const int k0 = kt << 5;
    const size_t colA = (size_t)(k0 + (l & 3) * 8);
    const int rb = w * 16 + (l >> 2);
#pragma unroll
    for (int c = 0; c < 2; ++c) {
      gl_lds16(A + (size_t)(m0 + c * 64 + rb) * (size_t)K + colA,
               &sA[buf][c * 2048 + w * 512]);
      gl_lds16(B + (size_t)(n0 + c * 64 + rb) * (size_t)K + colA,
               &sB[buf][c * 2048 + w * 512]);
    }
  };

  stage(0, 0);
  __syncthreads();

  for (int kt = 0; kt < NK; ++kt) {
    const int buf = kt & 1;
    if (kt + 1 < NK) stage(buf ^ 1, kt + 1);
    const int ro = (l & 15) * 32 + (l >> 4) * 8;
    short8 a[4], b[4];
#pragma unroll
    for (int f = 0; f < 4; ++f) {
      a[f] = *(const short8*)&sA[buf][(wr * 64 + f * 16) * 32 + ro];
      b[f] = *(const short8*)&sB[buf][(wc * 64 + f * 16) * 32 + ro];
    }
#pragma unroll
    for (int fi = 0; fi < 4; ++fi)
#pragma unroll
      for (int fj = 0; fj < 4; ++fj)
        acc[fi][fj] = __builtin_amdgcn_mfma_f32_16x16x32_bf16(
            a[fi], b[fj], acc[fi][fj], 0, 0, 0);
    __syncthreads();
  }

  const int r4 = (l >> 4) * 4, cc = l & 15;

  if constexpr (EPI == 1) {
#pragma unroll
    for (int fi = 0; fi < 4; ++fi)
#pragma unroll
      for (int r = 0; r < 4; ++r) {
        const size_t gm = (size_t)(m0 + wr * 64 + fi * 16 + r4 + r);
#pragma unroll
        for (int fj = 0; fj < 4; ++fj) {
          const int gn = n0 + wc * 64 + fj * 16 + cc;
          outBF[gm * (size_t)N + gn] = f2bf(acc[fi][fj][r]);
        }
      }
  } else {
    __shared__ ushortT tbuf[128 * 136];
#pragma unroll
    for (int fi = 0; fi < 4; ++fi)
#pragma unroll
      for (int r = 0; r < 4; ++r) {
        const int row = wr * 64 + fi * 16 + r4 + r;
        const size_t gm = (size_t)(m0 + row);
        float rs2 = 0.f, rs4 = 0.f;
#pragma unroll
        for (int fj = 0; fj < 4; ++fj) {
          const int col = wc * 64 + fj * 16 + cc;
          float sd = acc[fi][fj][r] + addend[gm * (size_t)N + n0 + col];
          tbuf[col * 136 + row] = f2bf(sd);
          float s2 = sd * sd;
          rs2 += s2;
          rs4 += s2 * s2;
        }
#pragma unroll
        for (int mk = 1; mk < 16; mk <<= 1) {
          rs2 += __shfl_xor(rs2, mk, 16);
          rs4 += __shfl_xor(rs4, mk, 16);
        }
        if (cc == 0) { atomicAdd(&S2[gm], rs2); atomicAdd(&S4[gm], rs4); }
      }
    __syncthreads();
#pragma unroll
    for (int i = 0; i < 8; ++i) {
      const int er = i * 16 + (tid >> 4);
      const int nc = (tid & 15) * 8;
      short8 v = *(const short8*)&tbuf[er * 136 + nc];
      *(short8*)&sdT[(size_t)(n0 + er) * (size_t)ldT + m0 + nc] = v;
    }
  }
}

// -------- 128x128 split-K GEMM for M = sdT sdT^T: partials, no scaling ------
__global__ __launch_bounds__(256) void mgemm128sk(
    const ushortT* __restrict__ T, int Dm, int K,
    float* __restrict__ pbuf)
{
  __shared__ ushortT sA[2][128 * 32];
  __shared__ ushortT sB[2][128 * 32];
  const int tid = threadIdx.x, w = tid >> 6, l = tid & 63;
  const int wr = w >> 1, wc = w & 1;
  const int i0 = blockIdx.x * 128, j0 = blockIdx.y * 128;
  const int kt0 = blockIdx.z * 64;
  f32x4 acc[4][4] = {};

  auto stage = [&](int buf, int kt) {
    const int k0 = kt << 5;
    const size_t col = (size_t)(k0 + (l & 3) * 8);
    const int rb = w * 16 + (l >> 2);
#pragma unroll
    for (int c = 0; c < 2; ++c) {
      gl_lds16(T + (size_t)(i0 + c * 64 + rb) * (size_t)K + col,
               &sA[buf][c * 2048 + w * 512]);
      gl_lds16(T + (size_t)(j0 + c * 64 + rb) * (size_t)K + col,
               &sB[buf][c * 2048 + w * 512]);
    }
  };

  stage(0, kt0);
  __syncthreads();

  for (int t = 0; t < 64; ++t) {
    const int buf = t & 1;
    if (t + 1 < 64) stage(buf ^ 1, kt0 + t + 1);
    const int ro = (l & 15) * 32 + (l >> 4) * 8;
    short8 a[4], b[4];
#pragma unroll
    for (int f = 0; f < 4; ++f) {
      a[f] = *(const short8*)&sA[buf][(wr * 64 + f * 16) * 32 + ro];
      b[f] = *(const short8*)&sB[buf][(wc * 64 + f * 16) * 32 + ro];
    }
#pragma unroll
    for (int fi = 0; fi < 4; ++fi)
#pragma unroll
      for (int fj = 0; fj < 4; ++fj)
        acc[fi][fj] = __builtin_amdgcn_mfma_f32_16x16x32_bf16(
            a[fi], b[fj], acc[fi][fj], 0, 0, 0);
    __syncthreads();
  }

  const int r4 = (l >> 4) * 4, cc = l & 15;
  float* out = pbuf + ((size_t)blockIdx.z << 20);
#pragma unroll
  for (int fi = 0; fi < 4; ++fi)
#pragma unroll
    for (int r = 0; r < 4; ++r) {
      const int gi = i0 + wr * 64 + fi * 16 + r4 + r;
#pragma unroll
      for (int fj = 0; fj < 4; ++fj) {
        const int gj = j0 + wc * 64 + fj * 16 + cc;
        out[(size_t)gi * (size_t)Dm + gj] = acc[fi][fj][r];
      }
    }
}

__global__ void reduce_grad(const float* __restrict__ pbuf,
                            float* __restrict__ grad, float invN) {
  const int i = blockIdx.x * 256 + threadIdx.x;
  const size_t base = (size_t)i * 4;
  f32x4 s = *(const f32x4*)(pbuf + base) + *(const f32x4*)(pbuf + base + (1u << 20)) +
            *(const f32x4*)(pbuf + base + (2u << 20)) + *(const f32x4*)(pbuf + base + (3u << 20));
  const int row = (int)(base >> 10), c0 = (int)(base & 1023);
  f32x4 o;
#pragma unroll
  for (int j = 0; j < 4; ++j)
    o[j] = 0.5f * (s[j] * invN) - ((row == c0 + j) ? 0.5f : 0.0f);
  *(f32x4*)(grad + base) = o;
}

// ---------------- small utility kernels -------------------------------------
__global__ void zero_f32(float* __restrict__ p, int n) {
  int i = blockIdx.x * blockDim.x + threadIdx.x;
  if (i < n) p[i] = 0.f;
}

__global__ void cvt_f32_bf16(const float* __restrict__ in, ushortT* __restrict__ out,
                             size_t n4) {
  size_t i = (size_t)blockIdx.x * blockDim.x + threadIdx.x;
  const size_t stride = (size_t)gridDim.x * blockDim.x;
  const f32x4* in4 = (const f32x4*)in;
  for (; i < n4; i += stride) {
    f32x4 v = __builtin_nontemporal_load(&in4[i]);
    us4 o = { f2bf(v.x), f2bf(v.y), f2bf(v.z), f2bf(v.w) };
    *(us4*)(out + i * 4) = o;
  }
}

// LDS-tiled coalesced transpose: qT[d][k] = bf16(q[k][d]). grid 8x8, 256 thr.
__global__ __launch_bounds__(256) void transposeQ(const float* __restrict__ q,
                                                  ushortT* __restrict__ qT) {
  __shared__ float t[128][129];
  const int bi = blockIdx.x, bj = blockIdx.y;
  const int tr = threadIdx.x >> 5, tc = threadIdx.x & 31;
#pragma unroll
  for (int i = 0; i < 16; ++i) {
    const int row = i * 8 + tr;
    f32x4 v = *(const f32x4*)&q[(size_t)(bi * 128 + row) * 1024 + bj * 128 + tc * 4];
#pragma unroll
    for (int j = 0; j < 4; ++j) t[row][tc * 4 + j] = v[j];
  }
  __syncthreads();
#pragma unroll
  for (int i = 0; i < 16; ++i) {
    const int dr = i * 8 + tr;
    us4 o = { f2bf(t[tc * 4 + 0][dr]), f2bf(t[tc * 4 + 1][dr]),
              f2bf(t[tc * 4 + 2][dr]), f2bf(t[tc * 4 + 3][dr]) };
    *(us4*)&qT[(size_t)(bj * 128 + dr) * 1024 + bi * 128 + tc * 4] = o;
  }
}

__global__ void make_p(const float* __restrict__ q, ushortT* __restrict__ p) {
  const int g = blockIdx.x * 256 + threadIdx.x;
  const size_t base = (size_t)g * 8;
  const int e = (int)(base >> 10);
  const int d0 = (int)(base & 1023);
  short8 v;
#pragma unroll
  for (int j = 0; j < 8; ++j) {
    float f = q[base + j] - ((e == d0 + j) ? 1.0f : 0.0f);
    v[j] = (short)f2bf(f);
  }
  *(short8*)(p + base) = v;
}

__global__ void gather_rows(const float* __restrict__ x, const int* __restrict__ idx,
                            float* __restrict__ self32, ushortT* __restrict__ selbf) {
  const int bid = blockIdx.x;
  const int b = bid >> 10;
  const int row = idx[bid] & 4095;
  const float4* src = (const float4*)(x + ((size_t)b * 4096 + (size_t)row) * 1024);
  const int t = threadIdx.x;
  float4 v = src[t];
  *(float4*)(self32 + (size_t)bid * 1024 + t * 4) = v;
  us4 o = { f2bf(v.x), f2bf(v.y), f2bf(v.z), f2bf(v.w) };
  *(us4*)(selbf + (size_t)bid * 1024 + t * 4) = o;
}

__global__ void loss_final(const float* __restrict__ S2, const float* __restrict__ S4,
                           float* __restrict__ out) {
  __shared__ double red0[256];
  __shared__ double red1[256];
  const int t = threadIdx.x;
  double ca = 0.0, wa = 0.0;
  for (int i = t; i < 8192; i += 256) {
    double s2 = (double)S2[i], s4 = (double)S4[i];
    ca += s2 * s2 - s4;
    wa += s4 - 2.0 * s2 + 1024.0;
  }
  red0[t] = ca; red1[t] = wa;
  __syncthreads();
  for (int s = 128; s > 0; s >>= 1) {
    if (t < s) { red0[t] += red0[t + s]; red1[t] += red1[t + s]; }
    __syncthreads();
  }
  if (t == 0) {
    const double inv = 1.0 / (8192.0 * 1024.0 * 1024.0);
    out[0] = (float)(red0[0] * inv);
    out[1] = (float)(red1[0] * inv);
  }
}

// ---------------- launch -----------------------------------------------------
extern "C" void kernel_launch(void* const* d_in, const int* in_sizes, int n_in,
                              void* d_out, int out_size, void* d_ws, size_t ws_size,
                              hipStream_t stream) {
  (void)in_sizes; (void)n_in; (void)out_size;
  const float* x = (const float*)d_in[0];
  const float* weight = (const float*)d_in[1];
  const float* bias = (const float*)d_in[2];
  const float* decorr = (const float*)d_in[3];
  const int* sidx = (const int*)d_in[4];

  if (ws_size < 146866176ULL) return;

  char* ws = (char*)d_ws;
  ushortT* xbf     = (ushortT*)(ws);
  ushortT* fusedbf = (ushortT*)(ws + 67108864);
  ushortT* wbf     = (ushortT*)(ws + 71303168);
  ushortT* qT      = (ushortT*)(ws + 75497472);
  ushortT* pbf     = (ushortT*)(ws + 77594624);
  float*   self32  = (float*)  (ws + 79691776);
  ushortT* selbf   = (ushortT*)(ws + 113246208);
  ushortT* sdT     = (ushortT*)(ws + 130023424);
  float*   S2      = (float*)  (ws + 146800640);
  float*   S4      = (float*)  (ws + 146833408);

  float* y = (float*)d_out;
  float* grad = y + 67108864ULL;
  float* losses = grad + 1048576ULL;

  zero_f32<<<dim3(64), dim3(256), 0, stream>>>(S2, 16384);
  cvt_f32_bf16<<<dim3(2048), dim3(256), 0, stream>>>(x, xbf, 8388608);
  cvt_f32_bf16<<<dim3(512), dim3(256), 0, stream>>>(weight, wbf, 524288);
  transposeQ<<<dim3(8, 8), dim3(256), 0, stream>>>(decorr, qT);
  make_p<<<dim3(512), dim3(256), 0, stream>>>(decorr, pbf);
  gather_rows<<<dim3(8192), dim3(256), 0, stream>>>(x, sidx, self32, selbf);

  // fused = W @ Q  ->  bf16
  gemm128<1><<<dim3(16, 8), dim3(256), 0, stream>>>(
      wbf, qT, 2048, 1024, 1024, nullptr, fusedbf, nullptr, nullptr,
      nullptr, nullptr, nullptr, 0);
  // y = x @ fused^T + bias  — 256x128 tile, 128x64/wave, 2 blocks/CU
  gemm256<<<dim3(2048), dim3(256), 0, stream>>>(
      xbf, fusedbf, 32768, 2048, 1024, y, bias);
  // sd = sel + sel @ P^T; S2/S4 row sums; sdT transposed bf16
  gemm128<2><<<dim3(64, 8), dim3(256), 0, stream>>>(
      selbf, pbf, 8192, 1024, 1024, nullptr, nullptr, nullptr, self32,
      S2, S4, sdT, 8192);
  // M partials = sdT sdT^T (split-K x4, 128^2 tiles), then reduce
  mgemm128sk<<<dim3(8, 8, 4), dim3(256), 0, stream>>>(sdT, 1024, 8192, self32);
  reduce_grad<<<dim3(1024), dim3(256), 0, stream>>>(self32, grad, 1.0f / 8192.0f);
  loss_final<<<dim3(1), dim3(256), 0, stream>>>(S2, S4, losses);
}